// Round 2
// baseline (804.168 us; speedup 1.0000x reference)
//
#include <hip/hip_runtime.h>
#include <math.h>

// Problem constants
#define NTOT 65536   // B*H*W = 64*32*32
#define KCB  1024
#define DIM  64

typedef float fvec2 __attribute__((ext_vector_type(2)));

// d_out layout (floats), concatenated return order
static const size_t OFF_Q    = 0;          // [64,64,32,32] = 4194304
static const size_t OFF_LOSS = 4194304;    // scalar
static const size_t OFF_PERP = 4194305;    // scalar
static const size_t OFF_ENC  = 4194306;    // [65536,1024] = 67108864
static const size_t OFF_EMB  = 71303170;   // [1024,64]
static const size_t OFF_NCS  = 71368706;   // [1024]
static const size_t OFF_NEMA = 71369730;   // [1024,64]

// ws layout (bytes)
static const size_t WSO_IDX   = 0;         // int[65536]
static const size_t WSO_ESQ   = 262144;    // float[1024]
static const size_t WSO_LOSSP = 266240;    // float[1024]
static const size_t WSO_CNT   = 270336;    // int[1024]
static const size_t WSO_SCAL  = 274432;    // float[8]
static const size_t WSO_ZC    = 278528;    // float[65536*64] (optional compact z)
static const size_t WS_NEED_ZC = 278528 + (size_t)NTOT * DIM * 4;

// ---------------------------------------------------------------------------
// K0: e_sq[k] = sum_d emb[k][d]^2
__global__ void k_esq(const float* __restrict__ emb, float* __restrict__ esq) {
    int k = blockIdx.x * 256 + threadIdx.x;   // grid 4x256 = 1024
    const float4* e4 = (const float4*)(emb + (size_t)k * 64);
    float a0 = 0.f, a1 = 0.f, a2 = 0.f, a3 = 0.f;
#pragma unroll
    for (int j = 0; j < 16; ++j) {
        float4 v = e4[j];
        a0 = fmaf(v.x, v.x, a0);
        a1 = fmaf(v.y, v.y, a1);
        a2 = fmaf(v.z, v.z, a2);
        a3 = fmaf(v.w, v.w, a3);
    }
    esq[k] = (a0 + a1) + (a2 + a3);
}

// ---------------------------------------------------------------------------
// K1: assignment + quantized + encodings + loss partial (+ optional compact z)
// 1024 blocks x 256 threads. Block handles 64 rows (same b), 4 waves split K.
__global__ __launch_bounds__(256, 4)
void k_assign(const float* __restrict__ ze, const float* __restrict__ emb,
              const float* __restrict__ esq, float* __restrict__ out,
              int* __restrict__ idx_out, float* __restrict__ lossp,
              float* __restrict__ zc, int use_zc) {
    __shared__ float zt[64 * 65];   // z tile transposed [d][row], padded
    __shared__ float sB[64 * 65];   // union: merge arrays -> qt -> loss red
    __shared__ int   sfidx[64];

    const int tid  = threadIdx.x;
    const int blk  = blockIdx.x;
    const int b    = blk >> 4;            // 16 blocks per batch image
    const int hw0  = (blk & 15) << 6;     // 64 hw positions per block
    const int n0   = blk << 6;            // == b*1024 + hw0
    const int lane = tid & 63;
    // wave id, forced into an SGPR so embedding-row loads become s_load
    const int part = __builtin_amdgcn_readfirstlane(tid >> 6);

    // ---- stage z tile (transposed, padded stride 65) ----
    for (int i = tid; i < 1024; i += 256) {
        int d = i >> 4, c4 = (i & 15) << 2;
        const float4 v = *(const float4*)(ze + ((size_t)((b << 6) + d) << 10) + hw0 + c4);
        zt[d * 65 + c4 + 0] = v.x;
        zt[d * 65 + c4 + 1] = v.y;
        zt[d * 65 + c4 + 2] = v.z;
        zt[d * 65 + c4 + 3] = v.w;
    }
    __syncthreads();

    // ---- z row into registers ----
    float z[64];
#pragma unroll
    for (int d = 0; d < 64; ++d) z[d] = zt[d * 65 + lane];

    // ---- distance argmin over this wave's K quarter (track top-2) ----
    float best = 3.4e38f, s2v = 3.4e38f;
    int i1 = 0, i2 = 0;
    const float4* emb4 = (const float4*)emb;
    const int k0 = part << 8;
    for (int kk = 0; kk < 256; ++kk) {
        const int k = k0 + kk;
        const float4* ep = emb4 + ((size_t)k << 4);
        float a0 = 0.f, a1 = 0.f, a2 = 0.f, a3 = 0.f;
#pragma unroll
        for (int j = 0; j < 16; ++j) {
            float4 ev = ep[j];               // uniform -> s_load_dwordx4
            a0 = fmaf(z[4 * j + 0], ev.x, a0);
            a1 = fmaf(z[4 * j + 1], ev.y, a1);
            a2 = fmaf(z[4 * j + 2], ev.z, a2);
            a3 = fmaf(z[4 * j + 3], ev.w, a3);
        }
        float dot = (a0 + a1) + (a2 + a3);
        float s = fmaf(dot, -2.0f, esq[k]);  // ||e||^2 - 2 z.e (row-const dropped)
        bool c1 = s < best;
        bool c2 = s < s2v;
        i2  = c1 ? i1 : (c2 ? k : i2);
        s2v = c1 ? best : (c2 ? s : s2v);
        i1  = c1 ? k : i1;
        best = c1 ? s : best;
    }

    // ---- merge 4 wave-partials per row ----
    float* mb  = sB;                 // [4][64]
    float* ms2 = sB + 256;
    int*   mi1 = (int*)(sB + 512);
    int*   mi2 = (int*)(sB + 768);
    mb [part * 64 + lane] = best;
    ms2[part * 64 + lane] = s2v;
    mi1[part * 64 + lane] = i1;
    mi2[part * 64 + lane] = i2;
    __syncthreads();

    if (tid < 64) {
        const int r = tid;
        float fb = mb[r], fs2 = ms2[r];
        int fi1 = mi1[r], fi2 = mi2[r];
#pragma unroll
        for (int p = 1; p < 4; ++p) {
            float ob = mb[p * 64 + r], os2 = ms2[p * 64 + r];
            int oi1 = mi1[p * 64 + r], oi2 = mi2[p * 64 + r];
            if (ob < fb)       { fs2 = fb; fi2 = fi1; fb = ob; fi1 = oi1; }
            else if (ob < fs2) { fs2 = ob; fi2 = oi1; }
            if (os2 < fs2)     { fs2 = os2; fi2 = oi2; }
        }
        // fp64 refine when fp32 can't resolve the top-2 gap
        if (fs2 - fb < 2e-2f) {
            double d1 = 0.0, d2 = 0.0;
            const float* e1 = emb + (size_t)fi1 * 64;
            const float* e2 = emb + (size_t)fi2 * 64;
            for (int d = 0; d < 64; ++d) {
                double zd = (double)zt[d * 65 + r];
                double q1 = zd - (double)e1[d];
                double q2 = zd - (double)e2[d];
                d1 += q1 * q1;
                d2 += q2 * q2;
            }
            if ((d2 < d1) || (d2 == d1 && fi2 < fi1)) fi1 = fi2;
        }
        sfidx[r] = fi1;
        idx_out[n0 + r] = fi1;
    }
    __syncthreads();

    // ---- post: quantized (via LDS transpose), loss partial, compact z ----
    float* qt = sB;   // merge data dead
    float lacc = 0.f;
    for (int i = tid; i < 4096; i += 256) {
        int r = i >> 6, d = i & 63;       // lanes: consecutive d, same row
        float e  = emb[(size_t)sfidx[r] * 64 + d];   // coalesced row read
        float zv = zt[d * 65 + r];
        float df = e - zv;
        lacc = fmaf(df, df, lacc);
        qt[d * 65 + r] = e;
        if (use_zc)
            __builtin_nontemporal_store(zv, &zc[(((size_t)(n0 + r)) << 6) + d]);
    }

    // ---- encodings: one-hot rows, fully written (8B nontemporal stores) ----
    fvec2* enc2 = (fvec2*)(out + OFF_ENC);
    for (int i = tid; i < 32768; i += 256) {     // 64 rows x 512 fvec2
        int r = i >> 9, c2 = i & 511;
        int fi = sfidx[r];
        int cb = c2 << 1;
        fvec2 v;
        v.x = (fi == cb)     ? 1.0f : 0.0f;
        v.y = (fi == cb + 1) ? 1.0f : 0.0f;
        __builtin_nontemporal_store(v, &enc2[(size_t)(n0 + r) * 512 + c2]);
    }
    __syncthreads();

    // ---- quantized store (coalesced via qt) ----
    for (int i = tid; i < 4096; i += 256) {
        int d = i >> 6, r = i & 63;       // lanes: consecutive rows, same d
        __builtin_nontemporal_store(
            qt[d * 65 + r],
            &out[OFF_Q + ((size_t)((b << 6) + d) << 10) + hw0 + r]);
    }
    __syncthreads();

    // ---- loss block reduce (fixed tree, deterministic) ----
    float* lred = sB;
    lred[tid] = lacc;
    __syncthreads();
    for (int s = 128; s > 0; s >>= 1) {
        if (tid < s) lred[tid] += lred[tid + s];
        __syncthreads();
    }
    if (tid == 0) lossp[blk] = lred[0];
}

// ---------------------------------------------------------------------------
// K3: per-code gather: counts[k], dw[k][:] -> new_ema_w, new_cluster_size
// 1024 blocks x 64 threads; deterministic fixed-order sums (no atomics).
__global__ __launch_bounds__(64)
void k_stats(const int* __restrict__ idx, const float* __restrict__ zcmp,
             const float* __restrict__ ze, const float* __restrict__ emaw,
             const float* __restrict__ ecs, float* __restrict__ out,
             int* __restrict__ counts, int use_zc) {
    const int k = blockIdx.x;
    const int t = threadIdx.x;
    float acc[64];
#pragma unroll
    for (int d = 0; d < 64; ++d) acc[d] = 0.f;
    int cnt = 0;
    for (int i = 0; i < 1024; ++i) {
        int n = (i << 6) + t;
        if (idx[n] == k) {
            ++cnt;
            if (use_zc) {
                const float4* zp = (const float4*)(zcmp + ((size_t)n << 6));
#pragma unroll
                for (int j = 0; j < 16; ++j) {
                    float4 v = zp[j];
                    acc[4 * j + 0] += v.x;
                    acc[4 * j + 1] += v.y;
                    acc[4 * j + 2] += v.z;
                    acc[4 * j + 3] += v.w;
                }
            } else {
                int bb = n >> 10, hw = n & 1023;
#pragma unroll
                for (int d = 0; d < 64; ++d)
                    acc[d] += ze[((size_t)((bb << 6) + d) << 10) + hw];
            }
        }
    }
    __shared__ float red[64 * 65];
    __shared__ int scnt[64];
#pragma unroll
    for (int d = 0; d < 64; ++d) red[t * 65 + d] = acc[d];
    scnt[t] = cnt;
    __syncthreads();
    float s = 0.f;
    for (int row = 0; row < 64; ++row) s += red[row * 65 + t];   // fixed order
    out[OFF_NEMA + ((size_t)k << 6) + t] = fmaf(0.01f, s, 0.99f * emaw[((size_t)k << 6) + t]);
    if (t == 0) {
        int c = 0;
        for (int r = 0; r < 64; ++r) c += scnt[r];
        counts[k] = c;
        out[OFF_NCS + k] = fmaf(0.01f, (float)c, 0.99f * ecs[k]);
    }
}

// ---------------------------------------------------------------------------
// K4a: scalars — loss, n = sum(new_cluster_size), perplexity
__global__ void k_scalars(const float* __restrict__ lossp, const int* __restrict__ counts,
                          const float* __restrict__ ncs, float* __restrict__ out,
                          float* __restrict__ scal) {
    __shared__ float sr[256];
    const int t = threadIdx.x;

    float v = lossp[t] + lossp[t + 256] + lossp[t + 512] + lossp[t + 768];
    sr[t] = v;
    __syncthreads();
    for (int s = 128; s > 0; s >>= 1) { if (t < s) sr[t] += sr[t + s]; __syncthreads(); }
    if (t == 0) out[OFF_LOSS] = sr[0] * (0.25f / 4194304.0f);
    __syncthreads();

    v = ncs[t] + ncs[t + 256] + ncs[t + 512] + ncs[t + 768];
    sr[t] = v;
    __syncthreads();
    for (int s = 128; s > 0; s >>= 1) { if (t < s) sr[t] += sr[t + s]; __syncthreads(); }
    if (t == 0) scal[0] = sr[0];
    __syncthreads();

    float pv = 0.f;
    for (int i = t; i < 1024; i += 256) {
        float p = (float)counts[i] * (1.0f / 65536.0f);
        pv += p * logf(p + 1e-10f);
    }
    sr[t] = pv;
    __syncthreads();
    for (int s = 128; s > 0; s >>= 1) { if (t < s) sr[t] += sr[t + s]; __syncthreads(); }
    if (t == 0) out[OFF_PERP] = expf(-sr[0]);
}

// ---------------------------------------------------------------------------
// K4b: new_embedding_w = new_ema_w / cluster_size
__global__ void k_embnorm(const float* __restrict__ nema, const float* __restrict__ ncs,
                          const float* __restrict__ scal, float* __restrict__ embw) {
    int i = blockIdx.x * 256 + threadIdx.x;   // 65536
    float n = scal[0];
    int k = i >> 6;
    float cs = (ncs[k] + 1e-10f) / (n + 1.024e-7f) * n;   // (ncs+EPS)/(n+K*EPS)*n
    embw[i] = nema[i] / cs;
}

// ---------------------------------------------------------------------------
extern "C" void kernel_launch(void* const* d_in, const int* in_sizes, int n_in,
                              void* d_out, int out_size, void* d_ws, size_t ws_size,
                              hipStream_t stream) {
    const float* ze   = (const float*)d_in[0];
    const float* emb  = (const float*)d_in[1];
    const float* ecs  = (const float*)d_in[2];
    const float* emaw = (const float*)d_in[3];
    float* out = (float*)d_out;
    char*  ws  = (char*)d_ws;

    int*   idx    = (int*)(ws + WSO_IDX);
    float* esq    = (float*)(ws + WSO_ESQ);
    float* lossp  = (float*)(ws + WSO_LOSSP);
    int*   counts = (int*)(ws + WSO_CNT);
    float* scal   = (float*)(ws + WSO_SCAL);
    float* zc     = (float*)(ws + WSO_ZC);
    const int use_zc = (ws_size >= WS_NEED_ZC) ? 1 : 0;

    k_esq    <<<4,    256, 0, stream>>>(emb, esq);
    k_assign <<<1024, 256, 0, stream>>>(ze, emb, esq, out, idx, lossp, zc, use_zc);
    k_stats  <<<1024, 64,  0, stream>>>(idx, zc, ze, emaw, ecs, out, counts, use_zc);
    k_scalars<<<1,    256, 0, stream>>>(lossp, counts, out + OFF_NCS, out, scal);
    k_embnorm<<<256,  256, 0, stream>>>(out + OFF_NEMA, out + OFF_NCS, scal, out + OFF_EMB);
}

// Round 3
// 332.643 us; speedup vs baseline: 2.4175x; 2.4175x over previous
//
#include <hip/hip_runtime.h>
#include <math.h>

// Problem constants
#define NTOT 65536   // B*H*W = 64*32*32
#define KCB  1024
#define DIM  64

typedef float fvec2 __attribute__((ext_vector_type(2)));

// d_out layout (floats), concatenated return order
static const size_t OFF_Q    = 0;          // [64,64,32,32] = 4194304
static const size_t OFF_LOSS = 4194304;    // scalar
static const size_t OFF_PERP = 4194305;    // scalar
static const size_t OFF_ENC  = 4194306;    // [65536,1024] = 67108864
static const size_t OFF_EMB  = 71303170;   // [1024,64]
static const size_t OFF_NCS  = 71368706;   // [1024]
static const size_t OFF_NEMA = 71369730;   // [1024,64]

// ws layout (bytes)
static const size_t WSO_IDX   = 0;         // int[65536]
static const size_t WSO_ESQ   = 262144;    // float[1024]
static const size_t WSO_LOSSP = 266240;    // float[1024]
static const size_t WSO_CNT   = 270336;    // int[1024]
static const size_t WSO_SCAL  = 274432;    // float[8]
static const size_t WSO_ZC    = 278528;    // float[65536*64] (optional compact z)
static const size_t WS_NEED_ZC = 278528 + (size_t)NTOT * DIM * 4;

// ---------------------------------------------------------------------------
// K0: e_sq[k] = sum_d emb[k][d]^2
__global__ void k_esq(const float* __restrict__ emb, float* __restrict__ esq) {
    int k = blockIdx.x * 256 + threadIdx.x;   // grid 4x256 = 1024
    const float4* e4 = (const float4*)(emb + (size_t)k * 64);
    float a0 = 0.f, a1 = 0.f, a2 = 0.f, a3 = 0.f;
#pragma unroll
    for (int j = 0; j < 16; ++j) {
        float4 v = e4[j];
        a0 = fmaf(v.x, v.x, a0);
        a1 = fmaf(v.y, v.y, a1);
        a2 = fmaf(v.z, v.z, a2);
        a3 = fmaf(v.w, v.w, a3);
    }
    esq[k] = (a0 + a1) + (a2 + a3);
}

// ---------------------------------------------------------------------------
// K1: assignment + quantized + encodings + loss partial (+ optional compact z)
// 1024 blocks x 256 threads. Block handles 64 rows (same b), 4 waves split K.
__global__ __launch_bounds__(256, 4)
void k_assign(const float* __restrict__ ze, const float* __restrict__ emb,
              const float* __restrict__ esq, float* __restrict__ out,
              int* __restrict__ idx_out, float* __restrict__ lossp,
              float* __restrict__ zc, int use_zc) {
    __shared__ float zt[64 * 65];   // z tile transposed [d][row], padded
    __shared__ float sB[64 * 65];   // union: merge arrays -> qt -> loss red
    __shared__ int   sfidx[64];

    const int tid  = threadIdx.x;
    const int blk  = blockIdx.x;
    const int b    = blk >> 4;            // 16 blocks per batch image
    const int hw0  = (blk & 15) << 6;     // 64 hw positions per block
    const int n0   = blk << 6;            // == b*1024 + hw0
    const int lane = tid & 63;
    // wave id, forced into an SGPR so embedding-row loads become s_load
    const int part = __builtin_amdgcn_readfirstlane(tid >> 6);

    // ---- stage z tile (transposed, padded stride 65) ----
    for (int i = tid; i < 1024; i += 256) {
        int d = i >> 4, c4 = (i & 15) << 2;
        const float4 v = *(const float4*)(ze + ((size_t)((b << 6) + d) << 10) + hw0 + c4);
        zt[d * 65 + c4 + 0] = v.x;
        zt[d * 65 + c4 + 1] = v.y;
        zt[d * 65 + c4 + 2] = v.z;
        zt[d * 65 + c4 + 3] = v.w;
    }
    __syncthreads();

    // ---- z row into registers ----
    float z[64];
#pragma unroll
    for (int d = 0; d < 64; ++d) z[d] = zt[d * 65 + lane];

    // ---- distance argmin over this wave's K quarter (track top-2) ----
    float best = 3.4e38f, s2v = 3.4e38f;
    int i1 = 0, i2 = 0;
    const float4* emb4 = (const float4*)emb;
    const int k0 = part << 8;
    for (int kk = 0; kk < 256; ++kk) {
        const int k = k0 + kk;
        const float4* ep = emb4 + ((size_t)k << 4);
        float a0 = 0.f, a1 = 0.f, a2 = 0.f, a3 = 0.f;
#pragma unroll
        for (int j = 0; j < 16; ++j) {
            float4 ev = ep[j];               // uniform -> s_load_dwordx4
            a0 = fmaf(z[4 * j + 0], ev.x, a0);
            a1 = fmaf(z[4 * j + 1], ev.y, a1);
            a2 = fmaf(z[4 * j + 2], ev.z, a2);
            a3 = fmaf(z[4 * j + 3], ev.w, a3);
        }
        float dot = (a0 + a1) + (a2 + a3);
        float s = fmaf(dot, -2.0f, esq[k]);  // ||e||^2 - 2 z.e (row-const dropped)
        bool c1 = s < best;
        bool c2 = s < s2v;
        i2  = c1 ? i1 : (c2 ? k : i2);
        s2v = c1 ? best : (c2 ? s : s2v);
        i1  = c1 ? k : i1;
        best = c1 ? s : best;
    }

    // ---- merge 4 wave-partials per row ----
    float* mb  = sB;                 // [4][64]
    float* ms2 = sB + 256;
    int*   mi1 = (int*)(sB + 512);
    int*   mi2 = (int*)(sB + 768);
    mb [part * 64 + lane] = best;
    ms2[part * 64 + lane] = s2v;
    mi1[part * 64 + lane] = i1;
    mi2[part * 64 + lane] = i2;
    __syncthreads();

    if (tid < 64) {
        const int r = tid;
        float fb = mb[r], fs2 = ms2[r];
        int fi1 = mi1[r], fi2 = mi2[r];
#pragma unroll
        for (int p = 1; p < 4; ++p) {
            float ob = mb[p * 64 + r], os2 = ms2[p * 64 + r];
            int oi1 = mi1[p * 64 + r], oi2 = mi2[p * 64 + r];
            if (ob < fb)       { fs2 = fb; fi2 = fi1; fb = ob; fi1 = oi1; }
            else if (ob < fs2) { fs2 = ob; fi2 = oi1; }
            if (os2 < fs2)     { fs2 = os2; fi2 = oi2; }
        }
        // fp64 refine when fp32 can't resolve the top-2 gap
        if (fs2 - fb < 2e-2f) {
            double d1 = 0.0, d2 = 0.0;
            const float* e1 = emb + (size_t)fi1 * 64;
            const float* e2 = emb + (size_t)fi2 * 64;
            for (int d = 0; d < 64; ++d) {
                double zd = (double)zt[d * 65 + r];
                double q1 = zd - (double)e1[d];
                double q2 = zd - (double)e2[d];
                d1 += q1 * q1;
                d2 += q2 * q2;
            }
            if ((d2 < d1) || (d2 == d1 && fi2 < fi1)) fi1 = fi2;
        }
        sfidx[r] = fi1;
        idx_out[n0 + r] = fi1;
    }
    __syncthreads();

    // ---- post: quantized (via LDS transpose), loss partial, compact z ----
    float* qt = sB;   // merge data dead
    float lacc = 0.f;
    for (int i = tid; i < 4096; i += 256) {
        int r = i >> 6, d = i & 63;       // lanes: consecutive d, same row
        float e  = emb[(size_t)sfidx[r] * 64 + d];   // coalesced row read
        float zv = zt[d * 65 + r];
        float df = e - zv;
        lacc = fmaf(df, df, lacc);
        qt[d * 65 + r] = e;
        if (use_zc)
            __builtin_nontemporal_store(zv, &zc[(((size_t)(n0 + r)) << 6) + d]);
    }

    // ---- encodings: one-hot rows, fully written (8B nontemporal stores) ----
    fvec2* enc2 = (fvec2*)(out + OFF_ENC);
    for (int i = tid; i < 32768; i += 256) {     // 64 rows x 512 fvec2
        int r = i >> 9, c2 = i & 511;
        int fi = sfidx[r];
        int cb = c2 << 1;
        fvec2 v;
        v.x = (fi == cb)     ? 1.0f : 0.0f;
        v.y = (fi == cb + 1) ? 1.0f : 0.0f;
        __builtin_nontemporal_store(v, &enc2[(size_t)(n0 + r) * 512 + c2]);
    }
    __syncthreads();

    // ---- quantized store (coalesced via qt) ----
    for (int i = tid; i < 4096; i += 256) {
        int d = i >> 6, r = i & 63;       // lanes: consecutive rows, same d
        __builtin_nontemporal_store(
            qt[d * 65 + r],
            &out[OFF_Q + ((size_t)((b << 6) + d) << 10) + hw0 + r]);
    }
    __syncthreads();

    // ---- loss block reduce (fixed tree, deterministic) ----
    float* lred = sB;
    lred[tid] = lacc;
    __syncthreads();
    for (int s = 128; s > 0; s >>= 1) {
        if (tid < s) lred[tid] += lred[tid + s];
        __syncthreads();
    }
    if (tid == 0) lossp[blk] = lred[0];
}

// ---------------------------------------------------------------------------
// K3 v2: per-code compact-then-gather. 1024 blocks x 256 threads.
// Chunked over n (16 chunks of 4096): count -> ordered compact to LDS ->
// 4 lane-groups gather z rows into register partials. Fixed combine order
// => deterministic, no float atomics.
__global__ __launch_bounds__(256)
void k_stats(const int* __restrict__ idx, const float* __restrict__ zcmp,
             const float* __restrict__ ze, const float* __restrict__ emaw,
             const float* __restrict__ ecs, float* __restrict__ out,
             int* __restrict__ counts, int use_zc) {
    const int k    = blockIdx.x;
    const int t    = threadIdx.x;
    const int g    = t >> 6;      // lane-group 0..3
    const int d    = t & 63;
    const int lane = t & 63;

    __shared__ int   s_list[4096];
    __shared__ int   s_wsum[4];
    __shared__ float s_red[4][64];

    float acc = 0.f;
    int totalM = 0;

    for (int chunk = 0; chunk < 16; ++chunk) {
        const int base = chunk << 12;              // 4096 entries/chunk
        const int nb   = base + (t << 4);          // this thread's 16 entries
        const int4* ip = (const int4*)(idx + nb);  // 64B aligned
        const int4 v0 = ip[0], v1 = ip[1], v2 = ip[2], v3 = ip[3];

        int c = 0;
        c += (v0.x == k) + (v0.y == k) + (v0.z == k) + (v0.w == k);
        c += (v1.x == k) + (v1.y == k) + (v1.z == k) + (v1.w == k);
        c += (v2.x == k) + (v2.y == k) + (v2.z == k) + (v2.w == k);
        c += (v3.x == k) + (v3.y == k) + (v3.z == k) + (v3.w == k);

        // intra-wave inclusive scan of c
        int inc = c;
#pragma unroll
        for (int off = 1; off < 64; off <<= 1) {
            int y = __shfl_up(inc, (unsigned)off, 64);
            if (lane >= off) inc += y;
        }
        if (lane == 63) s_wsum[g] = inc;
        __syncthreads();                            // (A) wsum ready; prev list reads done

        int wbase = 0;
#pragma unroll
        for (int w = 0; w < 4; ++w) wbase += (w < g) ? s_wsum[w] : 0;
        const int M = s_wsum[0] + s_wsum[1] + s_wsum[2] + s_wsum[3];
        int pos = wbase + inc - c;                  // exclusive offset, ordered by n

        if (v0.x == k) s_list[pos++] = nb + 0;
        if (v0.y == k) s_list[pos++] = nb + 1;
        if (v0.z == k) s_list[pos++] = nb + 2;
        if (v0.w == k) s_list[pos++] = nb + 3;
        if (v1.x == k) s_list[pos++] = nb + 4;
        if (v1.y == k) s_list[pos++] = nb + 5;
        if (v1.z == k) s_list[pos++] = nb + 6;
        if (v1.w == k) s_list[pos++] = nb + 7;
        if (v2.x == k) s_list[pos++] = nb + 8;
        if (v2.y == k) s_list[pos++] = nb + 9;
        if (v2.z == k) s_list[pos++] = nb + 10;
        if (v2.w == k) s_list[pos++] = nb + 11;
        if (v3.x == k) s_list[pos++] = nb + 12;
        if (v3.y == k) s_list[pos++] = nb + 13;
        if (v3.z == k) s_list[pos++] = nb + 14;
        if (v3.w == k) s_list[pos++] = nb + 15;
        __syncthreads();                            // (B) list ready

        // group g takes matches j = g, g+4, ... (fixed order -> deterministic)
        for (int j = g; j < M; j += 4) {
            int n = s_list[j];
            float zv;
            if (use_zc) zv = zcmp[((size_t)n << 6) + d];
            else        zv = ze[((((size_t)(n >> 10) << 6) + d) << 10) + (n & 1023)];
            acc += zv;
        }
        totalM += M;
        __syncthreads();                            // (C) list reads done
    }

    s_red[g][d] = acc;
    __syncthreads();
    if (g == 0) {
        float s = ((s_red[0][d] + s_red[1][d]) + s_red[2][d]) + s_red[3][d];
        out[OFF_NEMA + ((size_t)k << 6) + d] =
            fmaf(0.01f, s, 0.99f * emaw[((size_t)k << 6) + d]);
    }
    if (t == 0) {
        counts[k] = totalM;
        out[OFF_NCS + k] = fmaf(0.01f, (float)totalM, 0.99f * ecs[k]);
    }
}

// ---------------------------------------------------------------------------
// K4a: scalars — loss, n = sum(new_cluster_size), perplexity
__global__ void k_scalars(const float* __restrict__ lossp, const int* __restrict__ counts,
                          const float* __restrict__ ncs, float* __restrict__ out,
                          float* __restrict__ scal) {
    __shared__ float sr[256];
    const int t = threadIdx.x;

    float v = lossp[t] + lossp[t + 256] + lossp[t + 512] + lossp[t + 768];
    sr[t] = v;
    __syncthreads();
    for (int s = 128; s > 0; s >>= 1) { if (t < s) sr[t] += sr[t + s]; __syncthreads(); }
    if (t == 0) out[OFF_LOSS] = sr[0] * (0.25f / 4194304.0f);
    __syncthreads();

    v = ncs[t] + ncs[t + 256] + ncs[t + 512] + ncs[t + 768];
    sr[t] = v;
    __syncthreads();
    for (int s = 128; s > 0; s >>= 1) { if (t < s) sr[t] += sr[t + s]; __syncthreads(); }
    if (t == 0) scal[0] = sr[0];
    __syncthreads();

    float pv = 0.f;
    for (int i = t; i < 1024; i += 256) {
        float p = (float)counts[i] * (1.0f / 65536.0f);
        pv += p * logf(p + 1e-10f);
    }
    sr[t] = pv;
    __syncthreads();
    for (int s = 128; s > 0; s >>= 1) { if (t < s) sr[t] += sr[t + s]; __syncthreads(); }
    if (t == 0) out[OFF_PERP] = expf(-sr[0]);
}

// ---------------------------------------------------------------------------
// K4b: new_embedding_w = new_ema_w / cluster_size
__global__ void k_embnorm(const float* __restrict__ nema, const float* __restrict__ ncs,
                          const float* __restrict__ scal, float* __restrict__ embw) {
    int i = blockIdx.x * 256 + threadIdx.x;   // 65536
    float n = scal[0];
    int k = i >> 6;
    float cs = (ncs[k] + 1e-10f) / (n + 1.024e-7f) * n;   // (ncs+EPS)/(n+K*EPS)*n
    embw[i] = nema[i] / cs;
}

// ---------------------------------------------------------------------------
extern "C" void kernel_launch(void* const* d_in, const int* in_sizes, int n_in,
                              void* d_out, int out_size, void* d_ws, size_t ws_size,
                              hipStream_t stream) {
    const float* ze   = (const float*)d_in[0];
    const float* emb  = (const float*)d_in[1];
    const float* ecs  = (const float*)d_in[2];
    const float* emaw = (const float*)d_in[3];
    float* out = (float*)d_out;
    char*  ws  = (char*)d_ws;

    int*   idx    = (int*)(ws + WSO_IDX);
    float* esq    = (float*)(ws + WSO_ESQ);
    float* lossp  = (float*)(ws + WSO_LOSSP);
    int*   counts = (int*)(ws + WSO_CNT);
    float* scal   = (float*)(ws + WSO_SCAL);
    float* zc     = (float*)(ws + WSO_ZC);
    const int use_zc = (ws_size >= WS_NEED_ZC) ? 1 : 0;

    k_esq    <<<4,    256, 0, stream>>>(emb, esq);
    k_assign <<<1024, 256, 0, stream>>>(ze, emb, esq, out, idx, lossp, zc, use_zc);
    k_stats  <<<1024, 256, 0, stream>>>(idx, zc, ze, emaw, ecs, out, counts, use_zc);
    k_scalars<<<1,    256, 0, stream>>>(lossp, counts, out + OFF_NCS, out, scal);
    k_embnorm<<<256,  256, 0, stream>>>(out + OFF_NEMA, out + OFF_NCS, scal, out + OFF_EMB);
}

// Round 4
// 331.559 us; speedup vs baseline: 2.4254x; 1.0033x over previous
//
#include <hip/hip_runtime.h>
#include <math.h>

// Problem constants
#define NTOT 65536   // B*H*W = 64*32*32
#define KCB  1024
#define DIM  64

typedef float fvec2 __attribute__((ext_vector_type(2)));

// d_out layout (floats), concatenated return order
static const size_t OFF_Q    = 0;          // [64,64,32,32] = 4194304
static const size_t OFF_LOSS = 4194304;    // scalar
static const size_t OFF_PERP = 4194305;    // scalar
static const size_t OFF_ENC  = 4194306;    // [65536,1024] = 67108864
static const size_t OFF_EMB  = 71303170;   // [1024,64]
static const size_t OFF_NCS  = 71368706;   // [1024]
static const size_t OFF_NEMA = 71369730;   // [1024,64]

// ws layout (bytes)
static const size_t WSO_IDX   = 0;         // int[65536]
static const size_t WSO_ESQ   = 262144;    // float[1024]
static const size_t WSO_LOSSP = 266240;    // float[1024]
static const size_t WSO_CNT   = 270336;    // int[1024]
static const size_t WSO_SCAL  = 274432;    // float[8]
static const size_t WSO_ZC    = 278528;    // float[65536*64] (optional compact z)
static const size_t WS_NEED_ZC = 278528 + (size_t)NTOT * DIM * 4;

// ---------------------------------------------------------------------------
// K0: e_sq[k] = sum_d emb[k][d]^2
__global__ void k_esq(const float* __restrict__ emb, float* __restrict__ esq) {
    int k = blockIdx.x * 256 + threadIdx.x;   // grid 4x256 = 1024
    const float4* e4 = (const float4*)(emb + (size_t)k * 64);
    float a0 = 0.f, a1 = 0.f, a2 = 0.f, a3 = 0.f;
#pragma unroll
    for (int j = 0; j < 16; ++j) {
        float4 v = e4[j];
        a0 = fmaf(v.x, v.x, a0);
        a1 = fmaf(v.y, v.y, a1);
        a2 = fmaf(v.z, v.z, a2);
        a3 = fmaf(v.w, v.w, a3);
    }
    esq[k] = (a0 + a1) + (a2 + a3);
}

// ---------------------------------------------------------------------------
// K1: assignment + quantized + encodings + loss partial (+ optional compact z)
// 1024 blocks x 256 threads. Block handles 64 rows (same b), 4 waves split K.
// z row lives in 64 pinned VGPRs per lane (loaded straight from global,
// asm-pinned so regalloc cannot demote to LDS re-reads — round-3 lesson:
// VGPR_Count=52 proved z was LDS-resident, 2x slowdown).
__global__ __launch_bounds__(256, 4)
void k_assign(const float* __restrict__ ze, const float* __restrict__ emb,
              const float* __restrict__ esq, float* __restrict__ out,
              int* __restrict__ idx_out, float* __restrict__ lossp,
              float* __restrict__ zc, int use_zc) {
    __shared__ float zt[64 * 65];   // z tile transposed [d][row], padded
    __shared__ float sB[64 * 65];   // union: merge arrays -> qt -> loss red
    __shared__ int   sfidx[64];

    const int tid  = threadIdx.x;
    const int blk  = blockIdx.x;
    const int b    = blk >> 4;            // 16 blocks per batch image
    const int hw0  = (blk & 15) << 6;     // 64 hw positions per block
    const int n0   = blk << 6;            // == b*1024 + hw0
    const int lane = tid & 63;
    // wave id, forced into an SGPR so embedding-row loads become s_load
    const int part = __builtin_amdgcn_readfirstlane(tid >> 6);

    // ---- z row straight into registers (coalesced 256B per d) ----
    float z[64];
    const float* zb = ze + ((size_t)b << 16) + hw0 + lane;
#pragma unroll
    for (int d = 0; d < 64; ++d)
        z[d] = zb[(size_t)d << 10];

    // wave 0 mirrors its registers into LDS for the epilogue phases
    if (part == 0) {
#pragma unroll
        for (int d = 0; d < 64; ++d) zt[d * 65 + lane] = z[d];
    }

    // pin: force 64 live VGPRs; no LDS/global rematerialization possible
#pragma unroll
    for (int d = 0; d < 64; ++d) asm volatile("" : "+v"(z[d]));

    // ---- distance argmin over this wave's K quarter (track top-2) ----
    float best = 3.4e38f, s2v = 3.4e38f;
    int i1 = 0, i2 = 0;
    const float4* emb4 = (const float4*)emb;
    const int k0 = part << 8;
    for (int kk = 0; kk < 256; ++kk) {
        const int k = k0 + kk;
        const float4* ep = emb4 + ((size_t)k << 4);
        float a0 = 0.f, a1 = 0.f, a2 = 0.f, a3 = 0.f;
#pragma unroll
        for (int j = 0; j < 16; ++j) {
            float4 ev = ep[j];               // uniform -> s_load_dwordx4
            a0 = fmaf(z[4 * j + 0], ev.x, a0);
            a1 = fmaf(z[4 * j + 1], ev.y, a1);
            a2 = fmaf(z[4 * j + 2], ev.z, a2);
            a3 = fmaf(z[4 * j + 3], ev.w, a3);
        }
        float dot = (a0 + a1) + (a2 + a3);
        float s = fmaf(dot, -2.0f, esq[k]);  // ||e||^2 - 2 z.e (row-const dropped)
        bool c1 = s < best;
        bool c2 = s < s2v;
        i2  = c1 ? i1 : (c2 ? k : i2);
        s2v = c1 ? best : (c2 ? s : s2v);
        i1  = c1 ? k : i1;
        best = c1 ? s : best;
    }

    // ---- merge 4 wave-partials per row ----
    float* mb  = sB;                 // [4][64]
    float* ms2 = sB + 256;
    int*   mi1 = (int*)(sB + 512);
    int*   mi2 = (int*)(sB + 768);
    mb [part * 64 + lane] = best;
    ms2[part * 64 + lane] = s2v;
    mi1[part * 64 + lane] = i1;
    mi2[part * 64 + lane] = i2;
    __syncthreads();

    if (tid < 64) {
        const int r = tid;
        float fb = mb[r], fs2 = ms2[r];
        int fi1 = mi1[r], fi2 = mi2[r];
#pragma unroll
        for (int p = 1; p < 4; ++p) {
            float ob = mb[p * 64 + r], os2 = ms2[p * 64 + r];
            int oi1 = mi1[p * 64 + r], oi2 = mi2[p * 64 + r];
            if (ob < fb)       { fs2 = fb; fi2 = fi1; fb = ob; fi1 = oi1; }
            else if (ob < fs2) { fs2 = ob; fi2 = oi1; }
            if (os2 < fs2)     { fs2 = os2; fi2 = oi2; }
        }
        // fp64 refine when fp32 can't resolve the top-2 gap
        if (fs2 - fb < 2e-2f) {
            double d1 = 0.0, d2 = 0.0;
            const float* e1 = emb + (size_t)fi1 * 64;
            const float* e2 = emb + (size_t)fi2 * 64;
            for (int d = 0; d < 64; ++d) {
                double zd = (double)zt[d * 65 + r];
                double q1 = zd - (double)e1[d];
                double q2 = zd - (double)e2[d];
                d1 += q1 * q1;
                d2 += q2 * q2;
            }
            if ((d2 < d1) || (d2 == d1 && fi2 < fi1)) fi1 = fi2;
        }
        sfidx[r] = fi1;
        idx_out[n0 + r] = fi1;
    }
    __syncthreads();

    // ---- post: quantized (via LDS transpose), loss partial, compact z ----
    float* qt = sB;   // merge data dead
    float lacc = 0.f;
    for (int i = tid; i < 4096; i += 256) {
        int r = i >> 6, d = i & 63;       // lanes: consecutive d, same row
        float e  = emb[(size_t)sfidx[r] * 64 + d];   // coalesced row read
        float zv = zt[d * 65 + r];
        float df = e - zv;
        lacc = fmaf(df, df, lacc);
        qt[d * 65 + r] = e;
        if (use_zc)
            __builtin_nontemporal_store(zv, &zc[(((size_t)(n0 + r)) << 6) + d]);
    }

    // ---- encodings: one-hot rows, fully written (8B nontemporal stores) ----
    fvec2* enc2 = (fvec2*)(out + OFF_ENC);
    for (int i = tid; i < 32768; i += 256) {     // 64 rows x 512 fvec2
        int r = i >> 9, c2 = i & 511;
        int fi = sfidx[r];
        int cb = c2 << 1;
        fvec2 v;
        v.x = (fi == cb)     ? 1.0f : 0.0f;
        v.y = (fi == cb + 1) ? 1.0f : 0.0f;
        __builtin_nontemporal_store(v, &enc2[(size_t)(n0 + r) * 512 + c2]);
    }
    __syncthreads();

    // ---- quantized store (coalesced via qt) ----
    for (int i = tid; i < 4096; i += 256) {
        int d = i >> 6, r = i & 63;       // lanes: consecutive rows, same d
        __builtin_nontemporal_store(
            qt[d * 65 + r],
            &out[OFF_Q + ((size_t)((b << 6) + d) << 10) + hw0 + r]);
    }
    __syncthreads();

    // ---- loss block reduce (fixed tree, deterministic) ----
    float* lred = sB;
    lred[tid] = lacc;
    __syncthreads();
    for (int s = 128; s > 0; s >>= 1) {
        if (tid < s) lred[tid] += lred[tid + s];
        __syncthreads();
    }
    if (tid == 0) lossp[blk] = lred[0];
}

// ---------------------------------------------------------------------------
// K3 v2: per-code compact-then-gather. 1024 blocks x 256 threads.
// Chunked over n (16 chunks of 4096): count -> ordered compact to LDS ->
// 4 lane-groups gather z rows into register partials. Fixed combine order
// => deterministic, no float atomics.
__global__ __launch_bounds__(256)
void k_stats(const int* __restrict__ idx, const float* __restrict__ zcmp,
             const float* __restrict__ ze, const float* __restrict__ emaw,
             const float* __restrict__ ecs, float* __restrict__ out,
             int* __restrict__ counts, int use_zc) {
    const int k    = blockIdx.x;
    const int t    = threadIdx.x;
    const int g    = t >> 6;      // lane-group 0..3
    const int d    = t & 63;
    const int lane = t & 63;

    __shared__ int   s_list[4096];
    __shared__ int   s_wsum[4];
    __shared__ float s_red[4][64];

    float acc = 0.f;
    int totalM = 0;

    for (int chunk = 0; chunk < 16; ++chunk) {
        const int base = chunk << 12;              // 4096 entries/chunk
        const int nb   = base + (t << 4);          // this thread's 16 entries
        const int4* ip = (const int4*)(idx + nb);  // 64B aligned
        const int4 v0 = ip[0], v1 = ip[1], v2 = ip[2], v3 = ip[3];

        int c = 0;
        c += (v0.x == k) + (v0.y == k) + (v0.z == k) + (v0.w == k);
        c += (v1.x == k) + (v1.y == k) + (v1.z == k) + (v1.w == k);
        c += (v2.x == k) + (v2.y == k) + (v2.z == k) + (v2.w == k);
        c += (v3.x == k) + (v3.y == k) + (v3.z == k) + (v3.w == k);

        // intra-wave inclusive scan of c
        int inc = c;
#pragma unroll
        for (int off = 1; off < 64; off <<= 1) {
            int y = __shfl_up(inc, (unsigned)off, 64);
            if (lane >= off) inc += y;
        }
        if (lane == 63) s_wsum[g] = inc;
        __syncthreads();                            // (A) wsum ready; prev list reads done

        int wbase = 0;
#pragma unroll
        for (int w = 0; w < 4; ++w) wbase += (w < g) ? s_wsum[w] : 0;
        const int M = s_wsum[0] + s_wsum[1] + s_wsum[2] + s_wsum[3];
        int pos = wbase + inc - c;                  // exclusive offset, ordered by n

        if (v0.x == k) s_list[pos++] = nb + 0;
        if (v0.y == k) s_list[pos++] = nb + 1;
        if (v0.z == k) s_list[pos++] = nb + 2;
        if (v0.w == k) s_list[pos++] = nb + 3;
        if (v1.x == k) s_list[pos++] = nb + 4;
        if (v1.y == k) s_list[pos++] = nb + 5;
        if (v1.z == k) s_list[pos++] = nb + 6;
        if (v1.w == k) s_list[pos++] = nb + 7;
        if (v2.x == k) s_list[pos++] = nb + 8;
        if (v2.y == k) s_list[pos++] = nb + 9;
        if (v2.z == k) s_list[pos++] = nb + 10;
        if (v2.w == k) s_list[pos++] = nb + 11;
        if (v3.x == k) s_list[pos++] = nb + 12;
        if (v3.y == k) s_list[pos++] = nb + 13;
        if (v3.z == k) s_list[pos++] = nb + 14;
        if (v3.w == k) s_list[pos++] = nb + 15;
        __syncthreads();                            // (B) list ready

        // group g takes matches j = g, g+4, ... (fixed order -> deterministic)
        for (int j = g; j < M; j += 4) {
            int n = s_list[j];
            float zv;
            if (use_zc) zv = zcmp[((size_t)n << 6) + d];
            else        zv = ze[((((size_t)(n >> 10) << 6) + d) << 10) + (n & 1023)];
            acc += zv;
        }
        totalM += M;
        __syncthreads();                            // (C) list reads done
    }

    s_red[g][d] = acc;
    __syncthreads();
    if (g == 0) {
        float s = ((s_red[0][d] + s_red[1][d]) + s_red[2][d]) + s_red[3][d];
        out[OFF_NEMA + ((size_t)k << 6) + d] =
            fmaf(0.01f, s, 0.99f * emaw[((size_t)k << 6) + d]);
    }
    if (t == 0) {
        counts[k] = totalM;
        out[OFF_NCS + k] = fmaf(0.01f, (float)totalM, 0.99f * ecs[k]);
    }
}

// ---------------------------------------------------------------------------
// K4a: scalars — loss, n = sum(new_cluster_size), perplexity
__global__ void k_scalars(const float* __restrict__ lossp, const int* __restrict__ counts,
                          const float* __restrict__ ncs, float* __restrict__ out,
                          float* __restrict__ scal) {
    __shared__ float sr[256];
    const int t = threadIdx.x;

    float v = lossp[t] + lossp[t + 256] + lossp[t + 512] + lossp[t + 768];
    sr[t] = v;
    __syncthreads();
    for (int s = 128; s > 0; s >>= 1) { if (t < s) sr[t] += sr[t + s]; __syncthreads(); }
    if (t == 0) out[OFF_LOSS] = sr[0] * (0.25f / 4194304.0f);
    __syncthreads();

    v = ncs[t] + ncs[t + 256] + ncs[t + 512] + ncs[t + 768];
    sr[t] = v;
    __syncthreads();
    for (int s = 128; s > 0; s >>= 1) { if (t < s) sr[t] += sr[t + s]; __syncthreads(); }
    if (t == 0) scal[0] = sr[0];
    __syncthreads();

    float pv = 0.f;
    for (int i = t; i < 1024; i += 256) {
        float p = (float)counts[i] * (1.0f / 65536.0f);
        pv += p * logf(p + 1e-10f);
    }
    sr[t] = pv;
    __syncthreads();
    for (int s = 128; s > 0; s >>= 1) { if (t < s) sr[t] += sr[t + s]; __syncthreads(); }
    if (t == 0) out[OFF_PERP] = expf(-sr[0]);
}

// ---------------------------------------------------------------------------
// K4b: new_embedding_w = new_ema_w / cluster_size
__global__ void k_embnorm(const float* __restrict__ nema, const float* __restrict__ ncs,
                          const float* __restrict__ scal, float* __restrict__ embw) {
    int i = blockIdx.x * 256 + threadIdx.x;   // 65536
    float n = scal[0];
    int k = i >> 6;
    float cs = (ncs[k] + 1e-10f) / (n + 1.024e-7f) * n;   // (ncs+EPS)/(n+K*EPS)*n
    embw[i] = nema[i] / cs;
}

// ---------------------------------------------------------------------------
extern "C" void kernel_launch(void* const* d_in, const int* in_sizes, int n_in,
                              void* d_out, int out_size, void* d_ws, size_t ws_size,
                              hipStream_t stream) {
    const float* ze   = (const float*)d_in[0];
    const float* emb  = (const float*)d_in[1];
    const float* ecs  = (const float*)d_in[2];
    const float* emaw = (const float*)d_in[3];
    float* out = (float*)d_out;
    char*  ws  = (char*)d_ws;

    int*   idx    = (int*)(ws + WSO_IDX);
    float* esq    = (float*)(ws + WSO_ESQ);
    float* lossp  = (float*)(ws + WSO_LOSSP);
    int*   counts = (int*)(ws + WSO_CNT);
    float* scal   = (float*)(ws + WSO_SCAL);
    float* zc     = (float*)(ws + WSO_ZC);
    const int use_zc = (ws_size >= WS_NEED_ZC) ? 1 : 0;

    k_esq    <<<4,    256, 0, stream>>>(emb, esq);
    k_assign <<<1024, 256, 0, stream>>>(ze, emb, esq, out, idx, lossp, zc, use_zc);
    k_stats  <<<1024, 256, 0, stream>>>(idx, zc, ze, emaw, ecs, out, counts, use_zc);
    k_scalars<<<1,    256, 0, stream>>>(lossp, counts, out + OFF_NCS, out, scal);
    k_embnorm<<<256,  256, 0, stream>>>(out + OFF_NEMA, out + OFF_NCS, scal, out + OFF_EMB);
}

// Round 5
// 324.137 us; speedup vs baseline: 2.4809x; 1.0229x over previous
//
#include <hip/hip_runtime.h>
#include <math.h>

// Problem constants
#define NTOT 65536   // B*H*W = 64*32*32
#define KCB  1024
#define DIM  64

typedef float fvec2 __attribute__((ext_vector_type(2)));
typedef float fvec4 __attribute__((ext_vector_type(4)));

// d_out layout (floats), concatenated return order
static const size_t OFF_Q    = 0;          // [64,64,32,32] = 4194304
static const size_t OFF_LOSS = 4194304;    // scalar
static const size_t OFF_PERP = 4194305;    // scalar
static const size_t OFF_ENC  = 4194306;    // [65536,1024] = 67108864
static const size_t OFF_EMB  = 71303170;   // [1024,64]
static const size_t OFF_NCS  = 71368706;   // [1024]
static const size_t OFF_NEMA = 71369730;   // [1024,64]

// ws layout (bytes)
static const size_t WSO_IDX   = 0;         // int[65536]
static const size_t WSO_ESQ   = 262144;    // float[1024]
static const size_t WSO_LOSSP = 266240;    // float[1024]
static const size_t WSO_CNT   = 270336;    // int[1024]
static const size_t WSO_SCAL  = 274432;    // float[8]
static const size_t WSO_ZC    = 278528;    // float[65536*64] (optional compact z)
static const size_t WS_NEED_ZC = 278528 + (size_t)NTOT * DIM * 4;

// XOR-swizzled word index into a [64][64] fp32 LDS tile (16B-block swizzle):
// word = r*64 + ((d4 ^ ((r>>2)&15))<<2) + (d&3). All our access patterns
// (4-row b128 reads, 16-code b128 reads, row-sweep and col-sweep scalar
// phases) land at <=2 distinct addresses per bank -> conflict-free (m136).
__device__ __forceinline__ int swz(int r, int d) {
    return (r << 6) + ((((d >> 2) ^ ((r >> 2) & 15)) << 2) | (d & 3));
}

// ---------------------------------------------------------------------------
// K0: e_sq[k] = sum_d emb[k][d]^2
__global__ void k_esq(const float* __restrict__ emb, float* __restrict__ esq) {
    int k = blockIdx.x * 256 + threadIdx.x;   // grid 4x256 = 1024
    const float4* e4 = (const float4*)(emb + (size_t)k * 64);
    float a0 = 0.f, a1 = 0.f, a2 = 0.f, a3 = 0.f;
#pragma unroll
    for (int j = 0; j < 16; ++j) {
        float4 v = e4[j];
        a0 = fmaf(v.x, v.x, a0);
        a1 = fmaf(v.y, v.y, a1);
        a2 = fmaf(v.z, v.z, a2);
        a3 = fmaf(v.w, v.w, a3);
    }
    esq[k] = (a0 + a1) + (a2 + a3);
}

// ---------------------------------------------------------------------------
// K1: assignment + quantized + encodings + loss partial (+ compact z)
// 1024 blocks x 256 threads (4 waves). Register-tiled GEMM structure:
// wave w owns rows 16w..16w+15; lane (rg=lane>>4, cg=lane&15) owns a
// 4-row x 4-code micro-tile; codes swept in 16 tiles of 64 staged in LDS.
// Round-4 lesson: per-lane z[64] arrays spill (VGPR=52); 4x4 tiling keeps
// ~50 live regs and amortizes 8 fma per ds_read_b128.
__global__ __launch_bounds__(256, 4)
void k_assign(const float* __restrict__ ze, const float* __restrict__ emb,
              const float* __restrict__ esq, float* __restrict__ out,
              int* __restrict__ idx_out, float* __restrict__ lossp,
              float* __restrict__ zc, int use_zc) {
    __shared__ float zt[4096];    // z tile [row][d], swizzled
    __shared__ float etq[4096];   // union: e-tile -> merge arrays -> qt -> loss red
    __shared__ int   sfidx[64];

    const int tid  = threadIdx.x;
    const int blk  = blockIdx.x;
    const int b    = blk >> 4;            // 16 blocks per batch image
    const int hw0  = (blk & 15) << 6;     // 64 hw positions per block
    const int n0   = blk << 6;            // == b*1024 + hw0
    const int lane = tid & 63;
    const int part = tid >> 6;            // wave id 0..3
    const int rg   = lane >> 4;           // row group 0..3
    const int cg   = lane & 15;           // code group 0..15
    const int rbase = (part << 4) + (rg << 2);   // first of 4 rows
    const int rx    = (rbase >> 2) & 15;         // swizzle key (same for 4 rows)

    // ---- stage z tile: global (coalesced float4 over hw) -> swizzled LDS ----
#pragma unroll
    for (int j = 0; j < 4; ++j) {
        int idx = tid + (j << 8);
        int d = idx >> 4, r0 = (idx & 15) << 2;
        const fvec4 v = *(const fvec4*)(ze + (((size_t)(b << 6) + d) << 10) + hw0 + r0);
        zt[swz(r0 + 0, d)] = v.x;
        zt[swz(r0 + 1, d)] = v.y;
        zt[swz(r0 + 2, d)] = v.z;
        zt[swz(r0 + 3, d)] = v.w;
    }

    // ---- prefetch e tile 0 into regs (hidden under barrier) ----
    fvec4 pre[4];
#pragma unroll
    for (int j = 0; j < 4; ++j) {
        int idx = tid + (j << 8);
        int k = idx >> 4, d0 = (idx & 15) << 2;
        pre[j] = *(const fvec4*)(emb + ((size_t)k << 6) + d0);
    }
    __syncthreads();   // zt visible

    // ---- per-row top-2 tracking state ----
    float tb[4]  = {3.4e38f, 3.4e38f, 3.4e38f, 3.4e38f};
    float ts2[4] = {3.4e38f, 3.4e38f, 3.4e38f, 3.4e38f};
    int ti1[4] = {0, 0, 0, 0};
    int ti2[4] = {0, 0, 0, 0};

    for (int kt = 0; kt < 16; ++kt) {
        // ds_write current tile from prefetch regs
#pragma unroll
        for (int j = 0; j < 4; ++j) {
            int idx = tid + (j << 8);
            int k = idx >> 4, d0 = (idx & 15) << 2;
            *(fvec4*)&etq[swz(k, d0)] = pre[j];
        }
        __syncthreads();   // e tile visible

        // prefetch next tile (L2-resident; latency hides under compute)
        if (kt < 15) {
#pragma unroll
            for (int j = 0; j < 4; ++j) {
                int idx = tid + (j << 8);
                int k = idx >> 4, d0 = (idx & 15) << 2;
                pre[j] = *(const fvec4*)(emb + (((size_t)(kt + 1) << 6) + k) * 64 + d0);
            }
        }

        // ---- 4x4 micro-tile GEMM over d ----
        float acc[4][4];
#pragma unroll
        for (int i = 0; i < 4; ++i)
#pragma unroll
            for (int c = 0; c < 4; ++c) acc[i][c] = 0.f;

#pragma unroll 4
        for (int d4 = 0; d4 < 16; ++d4) {
            fvec4 zq[4], eq[4];
#pragma unroll
            for (int i = 0; i < 4; ++i)
                zq[i] = *(const fvec4*)&zt[((rbase + i) << 6) + (((d4 ^ rx) << 2))];
#pragma unroll
            for (int c = 0; c < 4; ++c)
                eq[c] = *(const fvec4*)&etq[(((cg << 2) + c) << 6) + (((d4 ^ cg) << 2))];
#pragma unroll
            for (int i = 0; i < 4; ++i)
#pragma unroll
                for (int c = 0; c < 4; ++c) {
                    acc[i][c] = fmaf(zq[i].x, eq[c].x, acc[i][c]);
                    acc[i][c] = fmaf(zq[i].y, eq[c].y, acc[i][c]);
                    acc[i][c] = fmaf(zq[i].z, eq[c].z, acc[i][c]);
                    acc[i][c] = fmaf(zq[i].w, eq[c].w, acc[i][c]);
                }
        }

        // ---- fold into top-2 (score = e_sq - 2*dot; row-const ||z||^2 dropped)
        const fvec4 es = *(const fvec4*)(esq + (kt << 6) + (cg << 2));
#pragma unroll
        for (int i = 0; i < 4; ++i) {
#pragma unroll
            for (int c = 0; c < 4; ++c) {
                float s = fmaf(acc[i][c], -2.0f,
                               (c == 0) ? es.x : (c == 1) ? es.y : (c == 2) ? es.z : es.w);
                int k = (kt << 6) + (cg << 2) + c;
                bool c1 = s < tb[i];
                bool c2 = s < ts2[i];
                ti2[i] = c1 ? ti1[i] : (c2 ? k : ti2[i]);
                ts2[i] = c1 ? tb[i] : (c2 ? s : ts2[i]);
                ti1[i] = c1 ? k : ti1[i];
                tb[i]  = c1 ? s : tb[i];
            }
        }
        __syncthreads();   // e tile readers done before next overwrite
    }

    // ---- merge 16 cg-partials per row (etq reused: [16][64] x4 arrays) ----
    float* mb  = etq;
    float* ms2 = etq + 1024;
    int*   mi1 = (int*)(etq + 2048);
    int*   mi2 = (int*)(etq + 3072);
#pragma unroll
    for (int i = 0; i < 4; ++i) {
        int row = rbase + i;
        mb [(cg << 6) + row] = tb[i];
        ms2[(cg << 6) + row] = ts2[i];
        mi1[(cg << 6) + row] = ti1[i];
        mi2[(cg << 6) + row] = ti2[i];
    }
    __syncthreads();

    if (tid < 64) {
        const int r = tid;
        float fb = mb[r], fs2 = ms2[r];
        int fi1 = mi1[r], fi2 = mi2[r];
#pragma unroll
        for (int p = 1; p < 16; ++p) {
            float ob = mb[(p << 6) + r], os2 = ms2[(p << 6) + r];
            int oi1 = mi1[(p << 6) + r], oi2 = mi2[(p << 6) + r];
            if (ob < fb)       { fs2 = fb; fi2 = fi1; fb = ob; fi1 = oi1; }
            else if (ob < fs2) { fs2 = ob; fi2 = oi1; }
            if (os2 < fs2)     { fs2 = os2; fi2 = oi2; }
        }
        // fp64 refine when fp32 can't resolve the top-2 gap
        if (fs2 - fb < 2e-2f) {
            double d1 = 0.0, d2 = 0.0;
            const float* e1 = emb + (size_t)fi1 * 64;
            const float* e2 = emb + (size_t)fi2 * 64;
            for (int d = 0; d < 64; ++d) {
                double zd = (double)zt[swz(r, d)];
                double q1 = zd - (double)e1[d];
                double q2 = zd - (double)e2[d];
                d1 += q1 * q1;
                d2 += q2 * q2;
            }
            if ((d2 < d1) || (d2 == d1 && fi2 < fi1)) fi1 = fi2;
        }
        sfidx[r] = fi1;
        idx_out[n0 + r] = fi1;
    }
    __syncthreads();

    // ---- post: quantized (qt in etq, swizzled [d][r]), loss, compact z ----
    float* qt = etq;   // merge arrays dead
    float lacc = 0.f;
    for (int i = tid; i < 4096; i += 256) {
        int r = i >> 6, d = i & 63;       // lanes: consecutive d, same row
        float e  = emb[(size_t)sfidx[r] * 64 + d];   // coalesced row read
        float zv = zt[swz(r, d)];
        float df = e - zv;
        lacc = fmaf(df, df, lacc);
        qt[swz(d, r)] = e;
        if (use_zc)
            __builtin_nontemporal_store(zv, &zc[(((size_t)(n0 + r)) << 6) + d]);
    }

    // ---- encodings: one-hot rows, fully written (8B nontemporal stores) ----
    fvec2* enc2 = (fvec2*)(out + OFF_ENC);
    for (int i = tid; i < 32768; i += 256) {     // 64 rows x 512 fvec2
        int r = i >> 9, c2 = i & 511;
        int fi = sfidx[r];
        int cb = c2 << 1;
        fvec2 v;
        v.x = (fi == cb)     ? 1.0f : 0.0f;
        v.y = (fi == cb + 1) ? 1.0f : 0.0f;
        __builtin_nontemporal_store(v, &enc2[(size_t)(n0 + r) * 512 + c2]);
    }
    __syncthreads();

    // ---- quantized store (coalesced via qt) ----
    for (int i = tid; i < 4096; i += 256) {
        int d = i >> 6, r = i & 63;       // lanes: consecutive rows, same d
        __builtin_nontemporal_store(
            qt[swz(d, r)],
            &out[OFF_Q + ((size_t)((b << 6) + d) << 10) + hw0 + r]);
    }
    __syncthreads();

    // ---- loss block reduce (fixed tree, deterministic) ----
    float* lred = etq;
    lred[tid] = lacc;
    __syncthreads();
    for (int s = 128; s > 0; s >>= 1) {
        if (tid < s) lred[tid] += lred[tid + s];
        __syncthreads();
    }
    if (tid == 0) lossp[blk] = lred[0];
}

// ---------------------------------------------------------------------------
// K3 v2: per-code compact-then-gather. 1024 blocks x 256 threads.
__global__ __launch_bounds__(256)
void k_stats(const int* __restrict__ idx, const float* __restrict__ zcmp,
             const float* __restrict__ ze, const float* __restrict__ emaw,
             const float* __restrict__ ecs, float* __restrict__ out,
             int* __restrict__ counts, int use_zc) {
    const int k    = blockIdx.x;
    const int t    = threadIdx.x;
    const int g    = t >> 6;      // lane-group 0..3
    const int d    = t & 63;
    const int lane = t & 63;

    __shared__ int   s_list[4096];
    __shared__ int   s_wsum[4];
    __shared__ float s_red[4][64];

    float acc = 0.f;
    int totalM = 0;

    for (int chunk = 0; chunk < 16; ++chunk) {
        const int base = chunk << 12;              // 4096 entries/chunk
        const int nb   = base + (t << 4);          // this thread's 16 entries
        const int4* ip = (const int4*)(idx + nb);  // 64B aligned
        const int4 v0 = ip[0], v1 = ip[1], v2 = ip[2], v3 = ip[3];

        int c = 0;
        c += (v0.x == k) + (v0.y == k) + (v0.z == k) + (v0.w == k);
        c += (v1.x == k) + (v1.y == k) + (v1.z == k) + (v1.w == k);
        c += (v2.x == k) + (v2.y == k) + (v2.z == k) + (v2.w == k);
        c += (v3.x == k) + (v3.y == k) + (v3.z == k) + (v3.w == k);

        int inc = c;
#pragma unroll
        for (int off = 1; off < 64; off <<= 1) {
            int y = __shfl_up(inc, (unsigned)off, 64);
            if (lane >= off) inc += y;
        }
        if (lane == 63) s_wsum[g] = inc;
        __syncthreads();                            // (A)

        int wbase = 0;
#pragma unroll
        for (int w = 0; w < 4; ++w) wbase += (w < g) ? s_wsum[w] : 0;
        const int M = s_wsum[0] + s_wsum[1] + s_wsum[2] + s_wsum[3];
        int pos = wbase + inc - c;                  // exclusive offset

        if (v0.x == k) s_list[pos++] = nb + 0;
        if (v0.y == k) s_list[pos++] = nb + 1;
        if (v0.z == k) s_list[pos++] = nb + 2;
        if (v0.w == k) s_list[pos++] = nb + 3;
        if (v1.x == k) s_list[pos++] = nb + 4;
        if (v1.y == k) s_list[pos++] = nb + 5;
        if (v1.z == k) s_list[pos++] = nb + 6;
        if (v1.w == k) s_list[pos++] = nb + 7;
        if (v2.x == k) s_list[pos++] = nb + 8;
        if (v2.y == k) s_list[pos++] = nb + 9;
        if (v2.z == k) s_list[pos++] = nb + 10;
        if (v2.w == k) s_list[pos++] = nb + 11;
        if (v3.x == k) s_list[pos++] = nb + 12;
        if (v3.y == k) s_list[pos++] = nb + 13;
        if (v3.z == k) s_list[pos++] = nb + 14;
        if (v3.w == k) s_list[pos++] = nb + 15;
        __syncthreads();                            // (B)

        for (int j = g; j < M; j += 4) {
            int n = s_list[j];
            float zv;
            if (use_zc) zv = zcmp[((size_t)n << 6) + d];
            else        zv = ze[((((size_t)(n >> 10) << 6) + d) << 10) + (n & 1023)];
            acc += zv;
        }
        totalM += M;
        __syncthreads();                            // (C)
    }

    s_red[g][d] = acc;
    __syncthreads();
    if (g == 0) {
        float s = ((s_red[0][d] + s_red[1][d]) + s_red[2][d]) + s_red[3][d];
        out[OFF_NEMA + ((size_t)k << 6) + d] =
            fmaf(0.01f, s, 0.99f * emaw[((size_t)k << 6) + d]);
    }
    if (t == 0) {
        counts[k] = totalM;
        out[OFF_NCS + k] = fmaf(0.01f, (float)totalM, 0.99f * ecs[k]);
    }
}

// ---------------------------------------------------------------------------
// K4a: scalars — loss, n = sum(new_cluster_size), perplexity
__global__ void k_scalars(const float* __restrict__ lossp, const int* __restrict__ counts,
                          const float* __restrict__ ncs, float* __restrict__ out,
                          float* __restrict__ scal) {
    __shared__ float sr[256];
    const int t = threadIdx.x;

    float v = lossp[t] + lossp[t + 256] + lossp[t + 512] + lossp[t + 768];
    sr[t] = v;
    __syncthreads();
    for (int s = 128; s > 0; s >>= 1) { if (t < s) sr[t] += sr[t + s]; __syncthreads(); }
    if (t == 0) out[OFF_LOSS] = sr[0] * (0.25f / 4194304.0f);
    __syncthreads();

    v = ncs[t] + ncs[t + 256] + ncs[t + 512] + ncs[t + 768];
    sr[t] = v;
    __syncthreads();
    for (int s = 128; s > 0; s >>= 1) { if (t < s) sr[t] += sr[t + s]; __syncthreads(); }
    if (t == 0) scal[0] = sr[0];
    __syncthreads();

    float pv = 0.f;
    for (int i = t; i < 1024; i += 256) {
        float p = (float)counts[i] * (1.0f / 65536.0f);
        pv += p * logf(p + 1e-10f);
    }
    sr[t] = pv;
    __syncthreads();
    for (int s = 128; s > 0; s >>= 1) { if (t < s) sr[t] += sr[t + s]; __syncthreads(); }
    if (t == 0) out[OFF_PERP] = expf(-sr[0]);
}

// ---------------------------------------------------------------------------
// K4b: new_embedding_w = new_ema_w / cluster_size
__global__ void k_embnorm(const float* __restrict__ nema, const float* __restrict__ ncs,
                          const float* __restrict__ scal, float* __restrict__ embw) {
    int i = blockIdx.x * 256 + threadIdx.x;   // 65536
    float n = scal[0];
    int k = i >> 6;
    float cs = (ncs[k] + 1e-10f) / (n + 1.024e-7f) * n;   // (ncs+EPS)/(n+K*EPS)*n
    embw[i] = nema[i] / cs;
}

// ---------------------------------------------------------------------------
extern "C" void kernel_launch(void* const* d_in, const int* in_sizes, int n_in,
                              void* d_out, int out_size, void* d_ws, size_t ws_size,
                              hipStream_t stream) {
    const float* ze   = (const float*)d_in[0];
    const float* emb  = (const float*)d_in[1];
    const float* ecs  = (const float*)d_in[2];
    const float* emaw = (const float*)d_in[3];
    float* out = (float*)d_out;
    char*  ws  = (char*)d_ws;

    int*   idx    = (int*)(ws + WSO_IDX);
    float* esq    = (float*)(ws + WSO_ESQ);
    float* lossp  = (float*)(ws + WSO_LOSSP);
    int*   counts = (int*)(ws + WSO_CNT);
    float* scal   = (float*)(ws + WSO_SCAL);
    float* zc     = (float*)(ws + WSO_ZC);
    const int use_zc = (ws_size >= WS_NEED_ZC) ? 1 : 0;

    k_esq    <<<4,    256, 0, stream>>>(emb, esq);
    k_assign <<<1024, 256, 0, stream>>>(ze, emb, esq, out, idx, lossp, zc, use_zc);
    k_stats  <<<1024, 256, 0, stream>>>(idx, zc, ze, emaw, ecs, out, counts, use_zc);
    k_scalars<<<1,    256, 0, stream>>>(lossp, counts, out + OFF_NCS, out, scal);
    k_embnorm<<<256,  256, 0, stream>>>(out + OFF_NEMA, out + OFF_NCS, scal, out + OFF_EMB);
}

// Round 6
// 279.040 us; speedup vs baseline: 2.8819x; 1.1616x over previous
//
#include <hip/hip_runtime.h>
#include <math.h>

// Problem constants
#define NTOT 65536   // B*H*W = 64*32*32
#define KCB  1024
#define DIM  64

typedef float fvec2 __attribute__((ext_vector_type(2)));
typedef float fvec4 __attribute__((ext_vector_type(4)));
typedef short sh8  __attribute__((ext_vector_type(8)));   // 8 bf16 = 4 VGPRs

// d_out layout (floats), concatenated return order
static const size_t OFF_Q    = 0;          // [64,64,32,32] = 4194304
static const size_t OFF_LOSS = 4194304;    // scalar
static const size_t OFF_PERP = 4194305;    // scalar
static const size_t OFF_ENC  = 4194306;    // [65536,1024] = 67108864
static const size_t OFF_EMB  = 71303170;   // [1024,64]
static const size_t OFF_NCS  = 71368706;   // [1024]
static const size_t OFF_NEMA = 71369730;   // [1024,64]

// ws layout (bytes)
static const size_t WSO_IDX   = 0;         // int[65536]
static const size_t WSO_ESQ   = 262144;    // float[1024]
static const size_t WSO_LOSSP = 266240;    // float[1024]
static const size_t WSO_CNT   = 270336;    // int[1024]
static const size_t WSO_SCAL  = 274432;    // float[8]
static const size_t WSO_EBH   = 278528;    // ushort[65536] e_hi, B-frag-major
static const size_t WSO_EBL   = 409600;    // ushort[65536] e_lo
static const size_t WSO_ZC    = 540672;    // float[65536*64] (optional compact z)
static const size_t WS_NEED_ZC = 540672 + (size_t)NTOT * DIM * 4;

// bf16 round-to-nearest-even split helpers
__device__ __forceinline__ unsigned short f2bf(float f) {
    unsigned u = __builtin_bit_cast(unsigned, f);
    return (unsigned short)((u + 0x7FFFu + ((u >> 16) & 1u)) >> 16);
}
__device__ __forceinline__ float bf2f(unsigned short h) {
    unsigned u = ((unsigned)h) << 16;
    return __builtin_bit_cast(float, u);
}

// XOR-swizzle for the qt transpose buffer (write/read self-consistent)
__device__ __forceinline__ int swz(int r, int d) {
    return (r << 6) + ((((d >> 2) ^ ((r >> 2) & 15)) << 2) | (d & 3));
}

// ---------------------------------------------------------------------------
// K0: e_sq[k] = sum_d emb[k][d]^2  (fp32, from ORIGINAL e — feeds scores)
__global__ void k_esq(const float* __restrict__ emb, float* __restrict__ esq) {
    int k = blockIdx.x * 256 + threadIdx.x;   // grid 4x256 = 1024
    const float4* e4 = (const float4*)(emb + (size_t)k * 64);
    float a0 = 0.f, a1 = 0.f, a2 = 0.f, a3 = 0.f;
#pragma unroll
    for (int j = 0; j < 16; ++j) {
        float4 v = e4[j];
        a0 = fmaf(v.x, v.x, a0);
        a1 = fmaf(v.y, v.y, a1);
        a2 = fmaf(v.z, v.z, a2);
        a3 = fmaf(v.w, v.w, a3);
    }
    esq[k] = (a0 + a1) + (a2 + a3);
}

// ---------------------------------------------------------------------------
// K0b: split e into bf16 hi/lo, stored B-fragment-major so a lane's B-frag
// for mfma_f32_16x16x32_bf16 is one contiguous 16B load:
//   elem (code c, k) -> [ (ct*2+kc)*64 + ko*16 + cl ]*8 + j
//   ct=c>>4, cl=c&15, kc=k>>5, ko=(k>>3)&3, j=k&7
__global__ void k_eprep(const float* __restrict__ emb,
                        unsigned short* __restrict__ ebh,
                        unsigned short* __restrict__ ebl) {
    int gid = blockIdx.x * 256 + threadIdx.x;   // 32x256 = 8192
    int c = gid >> 3, ko8 = gid & 7;
    const fvec4* p = (const fvec4*)(emb + ((size_t)c << 6) + (ko8 << 3));
    fvec4 v0 = p[0], v1 = p[1];
    float f[8] = {v0.x, v0.y, v0.z, v0.w, v1.x, v1.y, v1.z, v1.w};
    sh8 h, l;
#pragma unroll
    for (int j = 0; j < 8; ++j) {
        unsigned short hb = f2bf(f[j]);
        h[j] = (short)hb;
        l[j] = (short)f2bf(f[j] - bf2f(hb));
    }
    int ct = c >> 4, cl = c & 15, kc = ko8 >> 2, ko = ko8 & 3;
    size_t base = ((((size_t)ct << 1) + kc) << 9) + (((size_t)(ko << 4) + cl) << 3);
    *(sh8*)(ebh + base) = h;
    *(sh8*)(ebl + base) = l;
}

// ---------------------------------------------------------------------------
// K1: assignment via MFMA (bf16x3 split) + quantized + encodings + loss
// 1024 blocks x 256 threads (4 waves). Wave w owns rows w*16..w*16+15 and
// sweeps all 1024 codes in 64 tiles of 16. A-frags (z hi/lo) live in regs;
// B-frags stream from L2 (coalesced 16B/lane, depth-1 prefetch).
// Round-5 lesson: fp32 VALU GEMM is instruction-overhead-bound (~2.8x fma
// floor); matrix pipe + fp64-refine keeps argmin exact at MFMA speed.
__global__ __launch_bounds__(256, 4)
void k_assign(const float* __restrict__ ze, const float* __restrict__ emb,
              const float* __restrict__ esq,
              const unsigned short* __restrict__ ebh,
              const unsigned short* __restrict__ ebl,
              float* __restrict__ out,
              int* __restrict__ idx_out, float* __restrict__ lossp,
              float* __restrict__ zc, int use_zc) {
    __shared__ float zt[4096];    // z tile [row][d] fp32, plain
    __shared__ float etq[4096];   // union: merge arrays -> qt -> loss red
    __shared__ int   sfidx[64];

    const int tid  = threadIdx.x;
    const int blk  = blockIdx.x;
    const int b    = blk >> 4;            // 16 blocks per batch image
    const int hw0  = (blk & 15) << 6;     // 64 hw positions per block
    const int n0   = blk << 6;            // == b*1024 + hw0
    const int lane = tid & 63;
    const int wave = tid >> 6;            // 0..3
    const int cg   = lane & 15;           // C col within tile / A row low
    const int ko   = lane >> 4;           // k-chunk-octet selector

    // ---- stage z tile: global (coalesced float4 over hw) -> LDS [row][d] ----
#pragma unroll
    for (int j = 0; j < 4; ++j) {
        int idx = tid + (j << 8);
        int d = idx >> 4, r0 = (idx & 15) << 2;
        const fvec4 v = *(const fvec4*)(ze + (((size_t)(b << 6) + d) << 10) + hw0 + r0);
        zt[(r0 + 0) * 64 + d] = v.x;
        zt[(r0 + 1) * 64 + d] = v.y;
        zt[(r0 + 2) * 64 + d] = v.z;
        zt[(r0 + 3) * 64 + d] = v.w;
    }
    __syncthreads();

    // ---- A-fragments: z rows -> bf16 hi/lo in registers ----
    // lane's A row = wave*16 + cg; element j of chunk kc = k (kc*32 + ko*8 + j)
    const int arow = (wave << 4) + cg;
    sh8 Ah0, Ah1, Al0, Al1;
#pragma unroll
    for (int j = 0; j < 8; ++j) {
        float f0 = zt[arow * 64 + (ko << 3) + j];
        float f1 = zt[arow * 64 + 32 + (ko << 3) + j];
        unsigned short h0 = f2bf(f0), h1 = f2bf(f1);
        Ah0[j] = (short)h0;  Al0[j] = (short)f2bf(f0 - bf2f(h0));
        Ah1[j] = (short)h1;  Al1[j] = (short)f2bf(f1 - bf2f(h1));
    }

    // ---- per-row-slot top-2 tracking (4 C rows per lane) ----
    float tb[4]  = {3.4e38f, 3.4e38f, 3.4e38f, 3.4e38f};
    float ts2[4] = {3.4e38f, 3.4e38f, 3.4e38f, 3.4e38f};
    int ti1[4] = {0, 0, 0, 0};
    int ti2[4] = {0, 0, 0, 0};

    // ---- code-tile loop: 64 tiles of 16 codes, depth-1 B prefetch ----
    const size_t lb = (size_t)lane << 3;
    sh8 nbh0 = *(const sh8*)(ebh + lb);
    sh8 nbh1 = *(const sh8*)(ebh + 512 + lb);
    sh8 nbl0 = *(const sh8*)(ebl + lb);
    sh8 nbl1 = *(const sh8*)(ebl + 512 + lb);

    for (int ct = 0; ct < 64; ++ct) {
        sh8 bh0 = nbh0, bh1 = nbh1, bl0 = nbl0, bl1 = nbl1;
        if (ct < 63) {
            size_t o = ((size_t)(ct + 1) << 10) + lb;
            nbh0 = *(const sh8*)(ebh + o);
            nbh1 = *(const sh8*)(ebh + o + 512);
            nbl0 = *(const sh8*)(ebl + o);
            nbl1 = *(const sh8*)(ebl + o + 512);
        }
        fvec4 acc = {0.f, 0.f, 0.f, 0.f};
        acc = __builtin_amdgcn_mfma_f32_16x16x32_bf16(Ah0, bh0, acc, 0, 0, 0);
        acc = __builtin_amdgcn_mfma_f32_16x16x32_bf16(Ah1, bh1, acc, 0, 0, 0);
        acc = __builtin_amdgcn_mfma_f32_16x16x32_bf16(Ah0, bl0, acc, 0, 0, 0);
        acc = __builtin_amdgcn_mfma_f32_16x16x32_bf16(Ah1, bl1, acc, 0, 0, 0);
        acc = __builtin_amdgcn_mfma_f32_16x16x32_bf16(Al0, bh0, acc, 0, 0, 0);
        acc = __builtin_amdgcn_mfma_f32_16x16x32_bf16(Al1, bh1, acc, 0, 0, 0);

        // fold: lane's C col = code (ct*16+cg); rows = wave*16 + ko*4 + reg
        const int code = (ct << 4) + cg;
        const float es = esq[code];
#pragma unroll
        for (int rg = 0; rg < 4; ++rg) {
            float s = fmaf(acc[rg], -2.0f, es);
            bool c1 = s < tb[rg];
            bool c2 = s < ts2[rg];
            ti2[rg] = c1 ? ti1[rg] : (c2 ? code : ti2[rg]);
            ts2[rg] = c1 ? tb[rg] : (c2 ? s : ts2[rg]);
            ti1[rg] = c1 ? code : ti1[rg];
            tb[rg]  = c1 ? s : tb[rg];
        }
    }

    // ---- merge 16 col-lane partials per row (etq: [16][64] x4 arrays) ----
    float* mb  = etq;
    float* ms2 = etq + 1024;
    int*   mi1 = (int*)(etq + 2048);
    int*   mi2 = (int*)(etq + 3072);
#pragma unroll
    for (int rg = 0; rg < 4; ++rg) {
        int row = (wave << 4) + (ko << 2) + rg;
        mb [(cg << 6) + row] = tb[rg];
        ms2[(cg << 6) + row] = ts2[rg];
        mi1[(cg << 6) + row] = ti1[rg];
        mi2[(cg << 6) + row] = ti2[rg];
    }
    __syncthreads();

    if (tid < 64) {
        const int r = tid;
        float fb = mb[r], fs2 = ms2[r];
        int fi1 = mi1[r], fi2 = mi2[r];
#pragma unroll
        for (int p = 1; p < 16; ++p) {
            float ob = mb[(p << 6) + r], os2 = ms2[(p << 6) + r];
            int oi1 = mi1[(p << 6) + r], oi2 = mi2[(p << 6) + r];
            if (ob < fb)       { fs2 = fb; fi2 = fi1; fb = ob; fi1 = oi1; }
            else if (ob < fs2) { fs2 = ob; fi2 = oi1; }
            if (os2 < fs2)     { fs2 = os2; fi2 = oi2; }
        }
        // fp64 refine when approx scores can't resolve the top-2 gap
        // (bf16x3 error ~1e-4 << 2e-2 threshold)
        if (fs2 - fb < 2e-2f) {
            double d1 = 0.0, d2 = 0.0;
            const float* e1 = emb + (size_t)fi1 * 64;
            const float* e2 = emb + (size_t)fi2 * 64;
            for (int d = 0; d < 64; ++d) {
                double zd = (double)zt[r * 64 + d];
                double q1 = zd - (double)e1[d];
                double q2 = zd - (double)e2[d];
                d1 += q1 * q1;
                d2 += q2 * q2;
            }
            if ((d2 < d1) || (d2 == d1 && fi2 < fi1)) fi1 = fi2;
        }
        sfidx[r] = fi1;
        idx_out[n0 + r] = fi1;
    }
    __syncthreads();

    // ---- post: quantized (qt in etq, swizzled [d][r]), loss, compact z ----
    float* qt = etq;   // merge arrays dead
    float lacc = 0.f;
    for (int i = tid; i < 4096; i += 256) {
        int r = i >> 6, d = i & 63;       // lanes: consecutive d, same row
        float e  = emb[(size_t)sfidx[r] * 64 + d];   // coalesced row read
        float zv = zt[r * 64 + d];
        float df = e - zv;
        lacc = fmaf(df, df, lacc);
        qt[swz(d, r)] = e;
        if (use_zc)
            __builtin_nontemporal_store(zv, &zc[(((size_t)(n0 + r)) << 6) + d]);
    }

    // ---- encodings: one-hot rows, fully written (8B nontemporal stores) ----
    fvec2* enc2 = (fvec2*)(out + OFF_ENC);
    for (int i = tid; i < 32768; i += 256) {     // 64 rows x 512 fvec2
        int r = i >> 9, c2 = i & 511;
        int fi = sfidx[r];
        int cb = c2 << 1;
        fvec2 v;
        v.x = (fi == cb)     ? 1.0f : 0.0f;
        v.y = (fi == cb + 1) ? 1.0f : 0.0f;
        __builtin_nontemporal_store(v, &enc2[(size_t)(n0 + r) * 512 + c2]);
    }
    __syncthreads();

    // ---- quantized store (coalesced via qt) ----
    for (int i = tid; i < 4096; i += 256) {
        int d = i >> 6, r = i & 63;       // lanes: consecutive rows, same d
        __builtin_nontemporal_store(
            qt[swz(d, r)],
            &out[OFF_Q + ((size_t)((b << 6) + d) << 10) + hw0 + r]);
    }
    __syncthreads();

    // ---- loss block reduce (fixed tree, deterministic) ----
    float* lred = etq;
    lred[tid] = lacc;
    __syncthreads();
    for (int s = 128; s > 0; s >>= 1) {
        if (tid < s) lred[tid] += lred[tid + s];
        __syncthreads();
    }
    if (tid == 0) lossp[blk] = lred[0];
}

// ---------------------------------------------------------------------------
// K3 v2: per-code compact-then-gather. 1024 blocks x 256 threads.
__global__ __launch_bounds__(256)
void k_stats(const int* __restrict__ idx, const float* __restrict__ zcmp,
             const float* __restrict__ ze, const float* __restrict__ emaw,
             const float* __restrict__ ecs, float* __restrict__ out,
             int* __restrict__ counts, int use_zc) {
    const int k    = blockIdx.x;
    const int t    = threadIdx.x;
    const int g    = t >> 6;      // lane-group 0..3
    const int d    = t & 63;
    const int lane = t & 63;

    __shared__ int   s_list[4096];
    __shared__ int   s_wsum[4];
    __shared__ float s_red[4][64];

    float acc = 0.f;
    int totalM = 0;

    for (int chunk = 0; chunk < 16; ++chunk) {
        const int base = chunk << 12;              // 4096 entries/chunk
        const int nb   = base + (t << 4);          // this thread's 16 entries
        const int4* ip = (const int4*)(idx + nb);  // 64B aligned
        const int4 v0 = ip[0], v1 = ip[1], v2 = ip[2], v3 = ip[3];

        int c = 0;
        c += (v0.x == k) + (v0.y == k) + (v0.z == k) + (v0.w == k);
        c += (v1.x == k) + (v1.y == k) + (v1.z == k) + (v1.w == k);
        c += (v2.x == k) + (v2.y == k) + (v2.z == k) + (v2.w == k);
        c += (v3.x == k) + (v3.y == k) + (v3.z == k) + (v3.w == k);

        int inc = c;
#pragma unroll
        for (int off = 1; off < 64; off <<= 1) {
            int y = __shfl_up(inc, (unsigned)off, 64);
            if (lane >= off) inc += y;
        }
        if (lane == 63) s_wsum[g] = inc;
        __syncthreads();                            // (A)

        int wbase = 0;
#pragma unroll
        for (int w = 0; w < 4; ++w) wbase += (w < g) ? s_wsum[w] : 0;
        const int M = s_wsum[0] + s_wsum[1] + s_wsum[2] + s_wsum[3];
        int pos = wbase + inc - c;                  // exclusive offset

        if (v0.x == k) s_list[pos++] = nb + 0;
        if (v0.y == k) s_list[pos++] = nb + 1;
        if (v0.z == k) s_list[pos++] = nb + 2;
        if (v0.w == k) s_list[pos++] = nb + 3;
        if (v1.x == k) s_list[pos++] = nb + 4;
        if (v1.y == k) s_list[pos++] = nb + 5;
        if (v1.z == k) s_list[pos++] = nb + 6;
        if (v1.w == k) s_list[pos++] = nb + 7;
        if (v2.x == k) s_list[pos++] = nb + 8;
        if (v2.y == k) s_list[pos++] = nb + 9;
        if (v2.z == k) s_list[pos++] = nb + 10;
        if (v2.w == k) s_list[pos++] = nb + 11;
        if (v3.x == k) s_list[pos++] = nb + 12;
        if (v3.y == k) s_list[pos++] = nb + 13;
        if (v3.z == k) s_list[pos++] = nb + 14;
        if (v3.w == k) s_list[pos++] = nb + 15;
        __syncthreads();                            // (B)

        for (int j = g; j < M; j += 4) {
            int n = s_list[j];
            float zv;
            if (use_zc) zv = zcmp[((size_t)n << 6) + d];
            else        zv = ze[((((size_t)(n >> 10) << 6) + d) << 10) + (n & 1023)];
            acc += zv;
        }
        totalM += M;
        __syncthreads();                            // (C)
    }

    s_red[g][d] = acc;
    __syncthreads();
    if (g == 0) {
        float s = ((s_red[0][d] + s_red[1][d]) + s_red[2][d]) + s_red[3][d];
        out[OFF_NEMA + ((size_t)k << 6) + d] =
            fmaf(0.01f, s, 0.99f * emaw[((size_t)k << 6) + d]);
    }
    if (t == 0) {
        counts[k] = totalM;
        out[OFF_NCS + k] = fmaf(0.01f, (float)totalM, 0.99f * ecs[k]);
    }
}

// ---------------------------------------------------------------------------
// K4a: scalars — loss, n = sum(new_cluster_size), perplexity
__global__ void k_scalars(const float* __restrict__ lossp, const int* __restrict__ counts,
                          const float* __restrict__ ncs, float* __restrict__ out,
                          float* __restrict__ scal) {
    __shared__ float sr[256];
    const int t = threadIdx.x;

    float v = lossp[t] + lossp[t + 256] + lossp[t + 512] + lossp[t + 768];
    sr[t] = v;
    __syncthreads();
    for (int s = 128; s > 0; s >>= 1) { if (t < s) sr[t] += sr[t + s]; __syncthreads(); }
    if (t == 0) out[OFF_LOSS] = sr[0] * (0.25f / 4194304.0f);
    __syncthreads();

    v = ncs[t] + ncs[t + 256] + ncs[t + 512] + ncs[t + 768];
    sr[t] = v;
    __syncthreads();
    for (int s = 128; s > 0; s >>= 1) { if (t < s) sr[t] += sr[t + s]; __syncthreads(); }
    if (t == 0) scal[0] = sr[0];
    __syncthreads();

    float pv = 0.f;
    for (int i = t; i < 1024; i += 256) {
        float p = (float)counts[i] * (1.0f / 65536.0f);
        pv += p * logf(p + 1e-10f);
    }
    sr[t] = pv;
    __syncthreads();
    for (int s = 128; s > 0; s >>= 1) { if (t < s) sr[t] += sr[t + s]; __syncthreads(); }
    if (t == 0) out[OFF_PERP] = expf(-sr[0]);
}

// ---------------------------------------------------------------------------
// K4b: new_embedding_w = new_ema_w / cluster_size
__global__ void k_embnorm(const float* __restrict__ nema, const float* __restrict__ ncs,
                          const float* __restrict__ scal, float* __restrict__ embw) {
    int i = blockIdx.x * 256 + threadIdx.x;   // 65536
    float n = scal[0];
    int k = i >> 6;
    float cs = (ncs[k] + 1e-10f) / (n + 1.024e-7f) * n;   // (ncs+EPS)/(n+K*EPS)*n
    embw[i] = nema[i] / cs;
}

// ---------------------------------------------------------------------------
extern "C" void kernel_launch(void* const* d_in, const int* in_sizes, int n_in,
                              void* d_out, int out_size, void* d_ws, size_t ws_size,
                              hipStream_t stream) {
    const float* ze   = (const float*)d_in[0];
    const float* emb  = (const float*)d_in[1];
    const float* ecs  = (const float*)d_in[2];
    const float* emaw = (const float*)d_in[3];
    float* out = (float*)d_out;
    char*  ws  = (char*)d_ws;

    int*            idx    = (int*)(ws + WSO_IDX);
    float*          esq    = (float*)(ws + WSO_ESQ);
    float*          lossp  = (float*)(ws + WSO_LOSSP);
    int*            counts = (int*)(ws + WSO_CNT);
    float*          scal   = (float*)(ws + WSO_SCAL);
    unsigned short* ebh    = (unsigned short*)(ws + WSO_EBH);
    unsigned short* ebl    = (unsigned short*)(ws + WSO_EBL);
    float*          zc     = (float*)(ws + WSO_ZC);
    const int use_zc = (ws_size >= WS_NEED_ZC) ? 1 : 0;

    k_esq    <<<4,    256, 0, stream>>>(emb, esq);
    k_eprep  <<<32,   256, 0, stream>>>(emb, ebh, ebl);
    k_assign <<<1024, 256, 0, stream>>>(ze, emb, esq, ebh, ebl, out, idx, lossp, zc, use_zc);
    k_stats  <<<1024, 256, 0, stream>>>(idx, zc, ze, emaw, ecs, out, counts, use_zc);
    k_scalars<<<1,    256, 0, stream>>>(lossp, counts, out + OFF_NCS, out, scal);
    k_embnorm<<<256,  256, 0, stream>>>(out + OFF_NEMA, out + OFF_NCS, scal, out + OFF_EMB);
}

// Round 7
// 213.846 us; speedup vs baseline: 3.7605x; 1.3049x over previous
//
#include <hip/hip_runtime.h>
#include <math.h>

// Problem constants
#define NTOT 65536   // B*H*W = 64*32*32
#define KCB  1024
#define DIM  64

typedef float fvec2 __attribute__((ext_vector_type(2)));
typedef float fvec4 __attribute__((ext_vector_type(4)));
typedef short sh8  __attribute__((ext_vector_type(8)));   // 8 bf16 = 4 VGPRs

// d_out layout (floats), concatenated return order
static const size_t OFF_Q    = 0;          // [64,64,32,32] = 4194304
static const size_t OFF_LOSS = 4194304;    // scalar
static const size_t OFF_PERP = 4194305;    // scalar
static const size_t OFF_ENC  = 4194306;    // [65536,1024] = 67108864
static const size_t OFF_EMB  = 71303170;   // [1024,64]
static const size_t OFF_NCS  = 71368706;   // [1024]
static const size_t OFF_NEMA = 71369730;   // [1024,64]

// ws layout (bytes)
static const size_t WSO_IDX   = 0;         // int[65536]
static const size_t WSO_ESQ   = 262144;    // float[1024]
static const size_t WSO_LOSSP = 266240;    // float[1024]
static const size_t WSO_CNT   = 270336;    // int[1024]
static const size_t WSO_SCAL  = 274432;    // float[8]
static const size_t WSO_EBH   = 278528;    // ushort[65536] e_hi, B-frag-major
static const size_t WSO_EBL   = 409600;    // ushort[65536] e_lo
static const size_t WSO_ZC    = 540672;    // float[65536*64] (optional compact z)
static const size_t WS_NEED_ZC = 540672 + (size_t)NTOT * DIM * 4;

// bf16 round-to-nearest-even split helpers
__device__ __forceinline__ unsigned short f2bf(float f) {
    unsigned u = __builtin_bit_cast(unsigned, f);
    return (unsigned short)((u + 0x7FFFu + ((u >> 16) & 1u)) >> 16);
}
__device__ __forceinline__ float bf2f(unsigned short h) {
    unsigned u = ((unsigned)h) << 16;
    return __builtin_bit_cast(float, u);
}

// ---------------------------------------------------------------------------
// K0: split e into bf16 hi/lo (B-frag-major) + fused e_sq via 8-lane reduce.
// B-frag layout: elem (code c, k) -> [ (ct*2+kc)*64 + ko*16 + cl ]*8 + j
//   ct=c>>4, cl=c&15, kc=k>>5, ko=(k>>3)&3, j=k&7
__global__ void k_eprep(const float* __restrict__ emb,
                        unsigned short* __restrict__ ebh,
                        unsigned short* __restrict__ ebl,
                        float* __restrict__ esq) {
    int gid = blockIdx.x * 256 + threadIdx.x;   // 32x256 = 8192
    int c = gid >> 3, ko8 = gid & 7;
    const fvec4* p = (const fvec4*)(emb + ((size_t)c << 6) + (ko8 << 3));
    fvec4 v0 = p[0], v1 = p[1];
    float f[8] = {v0.x, v0.y, v0.z, v0.w, v1.x, v1.y, v1.z, v1.w};
    sh8 h, l;
    float sq0 = 0.f, sq1 = 0.f;
#pragma unroll
    for (int j = 0; j < 8; ++j) {
        unsigned short hb = f2bf(f[j]);
        h[j] = (short)hb;
        l[j] = (short)f2bf(f[j] - bf2f(hb));
        if (j < 4) sq0 = fmaf(f[j], f[j], sq0); else sq1 = fmaf(f[j], f[j], sq1);
    }
    float sq = sq0 + sq1;
    sq += __shfl_xor(sq, 1, 64);
    sq += __shfl_xor(sq, 2, 64);
    sq += __shfl_xor(sq, 4, 64);
    if (ko8 == 0) esq[c] = sq;

    int ct = c >> 4, cl = c & 15, kc = ko8 >> 2, ko = ko8 & 3;
    size_t base = ((((size_t)ct << 1) + kc) << 9) + (((size_t)(ko << 4) + cl) << 3);
    *(sh8*)(ebh + base) = h;
    *(sh8*)(ebl + base) = l;
}

// ---------------------------------------------------------------------------
// K1: assignment via MFMA (bf16x3 split) -> idx, loss partial, compact z.
// 1024 blocks x 256 threads (4 waves). Output streaming (encodings/quantized)
// moved to k_out so this kernel is compute-bound, not store-bound.
__global__ __launch_bounds__(256, 4)
void k_assign(const float* __restrict__ ze, const float* __restrict__ emb,
              const float* __restrict__ esq,
              const unsigned short* __restrict__ ebh,
              const unsigned short* __restrict__ ebl,
              int* __restrict__ idx_out, float* __restrict__ lossp,
              float* __restrict__ zc, int use_zc) {
    __shared__ float zt[4096];    // z tile [row][d] fp32
    __shared__ float etq[4096];   // merge arrays -> loss red
    __shared__ int   sfidx[64];

    const int tid  = threadIdx.x;
    const int blk  = blockIdx.x;
    const int b    = blk >> 4;            // 16 blocks per batch image
    const int hw0  = (blk & 15) << 6;     // 64 hw positions per block
    const int n0   = blk << 6;            // == b*1024 + hw0
    const int lane = tid & 63;
    const int wave = tid >> 6;            // 0..3
    const int cg   = lane & 15;           // C col within tile / A row low
    const int ko   = lane >> 4;           // k-chunk-octet selector

    // ---- stage z tile: global (coalesced float4 over hw) -> LDS [row][d] ----
#pragma unroll
    for (int j = 0; j < 4; ++j) {
        int idx = tid + (j << 8);
        int d = idx >> 4, r0 = (idx & 15) << 2;
        const fvec4 v = *(const fvec4*)(ze + (((size_t)(b << 6) + d) << 10) + hw0 + r0);
        zt[(r0 + 0) * 64 + d] = v.x;
        zt[(r0 + 1) * 64 + d] = v.y;
        zt[(r0 + 2) * 64 + d] = v.z;
        zt[(r0 + 3) * 64 + d] = v.w;
    }
    __syncthreads();

    // ---- A-fragments: z rows -> bf16 hi/lo in registers ----
    const int arow = (wave << 4) + cg;
    sh8 Ah0, Ah1, Al0, Al1;
#pragma unroll
    for (int j = 0; j < 8; ++j) {
        float f0 = zt[arow * 64 + (ko << 3) + j];
        float f1 = zt[arow * 64 + 32 + (ko << 3) + j];
        unsigned short h0 = f2bf(f0), h1 = f2bf(f1);
        Ah0[j] = (short)h0;  Al0[j] = (short)f2bf(f0 - bf2f(h0));
        Ah1[j] = (short)h1;  Al1[j] = (short)f2bf(f1 - bf2f(h1));
    }

    // ---- per-row-slot top-2 tracking (4 C rows per lane) ----
    float tb[4]  = {3.4e38f, 3.4e38f, 3.4e38f, 3.4e38f};
    float ts2[4] = {3.4e38f, 3.4e38f, 3.4e38f, 3.4e38f};
    int ti1[4] = {0, 0, 0, 0};
    int ti2[4] = {0, 0, 0, 0};

    // ---- code-tile loop: 64 tiles of 16 codes, depth-1 B prefetch ----
    const size_t lb = (size_t)lane << 3;
    sh8 nbh0 = *(const sh8*)(ebh + lb);
    sh8 nbh1 = *(const sh8*)(ebh + 512 + lb);
    sh8 nbl0 = *(const sh8*)(ebl + lb);
    sh8 nbl1 = *(const sh8*)(ebl + 512 + lb);

    for (int ct = 0; ct < 64; ++ct) {
        sh8 bh0 = nbh0, bh1 = nbh1, bl0 = nbl0, bl1 = nbl1;
        if (ct < 63) {
            size_t o = ((size_t)(ct + 1) << 10) + lb;
            nbh0 = *(const sh8*)(ebh + o);
            nbh1 = *(const sh8*)(ebh + o + 512);
            nbl0 = *(const sh8*)(ebl + o);
            nbl1 = *(const sh8*)(ebl + o + 512);
        }
        fvec4 acc = {0.f, 0.f, 0.f, 0.f};
        acc = __builtin_amdgcn_mfma_f32_16x16x32_bf16(Ah0, bh0, acc, 0, 0, 0);
        acc = __builtin_amdgcn_mfma_f32_16x16x32_bf16(Ah1, bh1, acc, 0, 0, 0);
        acc = __builtin_amdgcn_mfma_f32_16x16x32_bf16(Ah0, bl0, acc, 0, 0, 0);
        acc = __builtin_amdgcn_mfma_f32_16x16x32_bf16(Ah1, bl1, acc, 0, 0, 0);
        acc = __builtin_amdgcn_mfma_f32_16x16x32_bf16(Al0, bh0, acc, 0, 0, 0);
        acc = __builtin_amdgcn_mfma_f32_16x16x32_bf16(Al1, bh1, acc, 0, 0, 0);

        const int code = (ct << 4) + cg;
        const float es = esq[code];
#pragma unroll
        for (int rg = 0; rg < 4; ++rg) {
            float s = fmaf(acc[rg], -2.0f, es);
            bool c1 = s < tb[rg];
            bool c2 = s < ts2[rg];
            ti2[rg] = c1 ? ti1[rg] : (c2 ? code : ti2[rg]);
            ts2[rg] = c1 ? tb[rg] : (c2 ? s : ts2[rg]);
            ti1[rg] = c1 ? code : ti1[rg];
            tb[rg]  = c1 ? s : tb[rg];
        }
    }

    // ---- merge 16 col-lane partials per row (etq: [16][64] x4 arrays) ----
    float* mb  = etq;
    float* ms2 = etq + 1024;
    int*   mi1 = (int*)(etq + 2048);
    int*   mi2 = (int*)(etq + 3072);
#pragma unroll
    for (int rg = 0; rg < 4; ++rg) {
        int row = (wave << 4) + (ko << 2) + rg;
        mb [(cg << 6) + row] = tb[rg];
        ms2[(cg << 6) + row] = ts2[rg];
        mi1[(cg << 6) + row] = ti1[rg];
        mi2[(cg << 6) + row] = ti2[rg];
    }
    __syncthreads();

    if (tid < 64) {
        const int r = tid;
        float fb = mb[r], fs2 = ms2[r];
        int fi1 = mi1[r], fi2 = mi2[r];
#pragma unroll
        for (int p = 1; p < 16; ++p) {
            float ob = mb[(p << 6) + r], os2 = ms2[(p << 6) + r];
            int oi1 = mi1[(p << 6) + r], oi2 = mi2[(p << 6) + r];
            if (ob < fb)       { fs2 = fb; fi2 = fi1; fb = ob; fi1 = oi1; }
            else if (ob < fs2) { fs2 = ob; fi2 = oi1; }
            if (os2 < fs2)     { fs2 = os2; fi2 = oi2; }
        }
        // fp64 refine when approx scores can't resolve the top-2 gap
        if (fs2 - fb < 2e-2f) {
            double d1 = 0.0, d2 = 0.0;
            const float* e1 = emb + (size_t)fi1 * 64;
            const float* e2 = emb + (size_t)fi2 * 64;
            for (int d = 0; d < 64; ++d) {
                double zd = (double)zt[r * 64 + d];
                double q1 = zd - (double)e1[d];
                double q2 = zd - (double)e2[d];
                d1 += q1 * q1;
                d2 += q2 * q2;
            }
            if ((d2 < d1) || (d2 == d1 && fi2 < fi1)) fi1 = fi2;
        }
        sfidx[r] = fi1;
        idx_out[n0 + r] = fi1;
    }
    __syncthreads();

    // ---- loss partial + compact z (cached stores: k_stats re-reads zc) ----
    float lacc = 0.f;
    for (int i = tid; i < 4096; i += 256) {
        int r = i >> 6, d = i & 63;       // wave owns row r, lanes over d
        float e  = emb[(size_t)sfidx[r] * 64 + d];   // coalesced row read
        float zv = zt[r * 64 + d];
        float df = e - zv;
        lacc = fmaf(df, df, lacc);
        if (use_zc) zc[(((size_t)(n0 + r)) << 6) + d] = zv;
    }
    __syncthreads();

    // ---- loss block reduce (fixed tree, deterministic) ----
    float* lred = etq;
    lred[tid] = lacc;
    __syncthreads();
    for (int s = 128; s > 0; s >>= 1) {
        if (tid < s) lred[tid] += lred[tid + s];
        __syncthreads();
    }
    if (tid == 0) lossp[blk] = lred[0];
}

// ---------------------------------------------------------------------------
// K2: output streaming — encodings one-hot (268 MB) + quantized (16.8 MB).
// Pure write-bound; reads idx + emb from L2. 1024 blocks x 256 threads.
__global__ __launch_bounds__(256)
void k_out(const int* __restrict__ idx, const float* __restrict__ emb,
           float* __restrict__ out) {
    __shared__ int   sfidx[64];
    __shared__ float qt[64 * 65];   // [d][r], padded

    const int tid = threadIdx.x;
    const int blk = blockIdx.x;
    const int b   = blk >> 4;
    const int hw0 = (blk & 15) << 6;
    const int n0  = blk << 6;

    if (tid < 64) sfidx[tid] = idx[n0 + tid];
    __syncthreads();

    // emb gather, coalesced per row; transpose via padded LDS
    for (int i = tid; i < 4096; i += 256) {
        int r = i >> 6, d = i & 63;
        qt[d * 65 + r] = emb[(size_t)sfidx[r] * 64 + d];
    }

    // encodings: one-hot rows, fully written (8B nontemporal stores)
    fvec2* enc2 = (fvec2*)(out + OFF_ENC);
    for (int i = tid; i < 32768; i += 256) {     // 64 rows x 512 fvec2
        int r = i >> 9, c2 = i & 511;
        int fi = sfidx[r];
        int cb = c2 << 1;
        fvec2 v;
        v.x = (fi == cb)     ? 1.0f : 0.0f;
        v.y = (fi == cb + 1) ? 1.0f : 0.0f;
        __builtin_nontemporal_store(v, &enc2[(size_t)(n0 + r) * 512 + c2]);
    }
    __syncthreads();

    // quantized store (BCHW, coalesced over hw via qt)
    for (int i = tid; i < 4096; i += 256) {
        int d = i >> 6, r = i & 63;
        __builtin_nontemporal_store(
            qt[d * 65 + r],
            &out[OFF_Q + ((size_t)((b << 6) + d) << 10) + hw0 + r]);
    }
}

// ---------------------------------------------------------------------------
// K3: per-code compact-then-gather, 4-deep ILP gather (round-6 lesson:
// 1-deep dependent gathers were latency-bound). 1024 blocks x 256 threads.
__global__ __launch_bounds__(256)
void k_stats(const int* __restrict__ idx, const float* __restrict__ zcmp,
             const float* __restrict__ ze, const float* __restrict__ emaw,
             const float* __restrict__ ecs, float* __restrict__ out,
             int* __restrict__ counts, int use_zc) {
    const int k    = blockIdx.x;
    const int t    = threadIdx.x;
    const int g    = t >> 6;      // lane-group 0..3
    const int d    = t & 63;
    const int lane = t & 63;

    __shared__ int   s_list[4096];
    __shared__ int   s_wsum[4];
    __shared__ float s_red[4][64];

#define ZLOAD(n) (use_zc ? zcmp[((size_t)(n) << 6) + d] \
                         : ze[((((size_t)((n) >> 10) << 6) + d) << 10) + ((n) & 1023)])

    float a0 = 0.f, a1 = 0.f, a2 = 0.f, a3 = 0.f;
    int totalM = 0;

    for (int chunk = 0; chunk < 16; ++chunk) {
        const int base = chunk << 12;              // 4096 entries/chunk
        const int nb   = base + (t << 4);          // this thread's 16 entries
        const int4* ip = (const int4*)(idx + nb);  // 64B aligned
        const int4 v0 = ip[0], v1 = ip[1], v2 = ip[2], v3 = ip[3];

        int c = 0;
        c += (v0.x == k) + (v0.y == k) + (v0.z == k) + (v0.w == k);
        c += (v1.x == k) + (v1.y == k) + (v1.z == k) + (v1.w == k);
        c += (v2.x == k) + (v2.y == k) + (v2.z == k) + (v2.w == k);
        c += (v3.x == k) + (v3.y == k) + (v3.z == k) + (v3.w == k);

        int inc = c;
#pragma unroll
        for (int off = 1; off < 64; off <<= 1) {
            int y = __shfl_up(inc, (unsigned)off, 64);
            if (lane >= off) inc += y;
        }
        if (lane == 63) s_wsum[g] = inc;
        __syncthreads();                            // (A)

        int wbase = 0;
#pragma unroll
        for (int w = 0; w < 4; ++w) wbase += (w < g) ? s_wsum[w] : 0;
        const int M = s_wsum[0] + s_wsum[1] + s_wsum[2] + s_wsum[3];
        int pos = wbase + inc - c;                  // exclusive offset

        if (v0.x == k) s_list[pos++] = nb + 0;
        if (v0.y == k) s_list[pos++] = nb + 1;
        if (v0.z == k) s_list[pos++] = nb + 2;
        if (v0.w == k) s_list[pos++] = nb + 3;
        if (v1.x == k) s_list[pos++] = nb + 4;
        if (v1.y == k) s_list[pos++] = nb + 5;
        if (v1.z == k) s_list[pos++] = nb + 6;
        if (v1.w == k) s_list[pos++] = nb + 7;
        if (v2.x == k) s_list[pos++] = nb + 8;
        if (v2.y == k) s_list[pos++] = nb + 9;
        if (v2.z == k) s_list[pos++] = nb + 10;
        if (v2.w == k) s_list[pos++] = nb + 11;
        if (v3.x == k) s_list[pos++] = nb + 12;
        if (v3.y == k) s_list[pos++] = nb + 13;
        if (v3.z == k) s_list[pos++] = nb + 14;
        if (v3.w == k) s_list[pos++] = nb + 15;
        __syncthreads();                            // (B)

        // group g takes j = g, g+4, ...; 4-deep unroll -> 4 loads in flight
        int j = g;
        for (; j + 12 < M; j += 16) {
            int n0_ = s_list[j], n1_ = s_list[j + 4];
            int n2_ = s_list[j + 8], n3_ = s_list[j + 12];
            float z0 = ZLOAD(n0_), z1 = ZLOAD(n1_);
            float z2 = ZLOAD(n2_), z3 = ZLOAD(n3_);
            a0 += z0; a1 += z1; a2 += z2; a3 += z3;
        }
        for (; j < M; j += 4) a0 += ZLOAD(s_list[j]);
        totalM += M;
        __syncthreads();                            // (C)
    }
#undef ZLOAD

    s_red[g][d] = (a0 + a1) + (a2 + a3);
    __syncthreads();
    if (g == 0) {
        float s = ((s_red[0][d] + s_red[1][d]) + s_red[2][d]) + s_red[3][d];
        out[OFF_NEMA + ((size_t)k << 6) + d] =
            fmaf(0.01f, s, 0.99f * emaw[((size_t)k << 6) + d]);
    }
    if (t == 0) {
        counts[k] = totalM;
        out[OFF_NCS + k] = fmaf(0.01f, (float)totalM, 0.99f * ecs[k]);
    }
}

// ---------------------------------------------------------------------------
// K4a: scalars — loss, n = sum(new_cluster_size), perplexity
__global__ void k_scalars(const float* __restrict__ lossp, const int* __restrict__ counts,
                          const float* __restrict__ ncs, float* __restrict__ out,
                          float* __restrict__ scal) {
    __shared__ float sr[256];
    const int t = threadIdx.x;

    float v = lossp[t] + lossp[t + 256] + lossp[t + 512] + lossp[t + 768];
    sr[t] = v;
    __syncthreads();
    for (int s = 128; s > 0; s >>= 1) { if (t < s) sr[t] += sr[t + s]; __syncthreads(); }
    if (t == 0) out[OFF_LOSS] = sr[0] * (0.25f / 4194304.0f);
    __syncthreads();

    v = ncs[t] + ncs[t + 256] + ncs[t + 512] + ncs[t + 768];
    sr[t] = v;
    __syncthreads();
    for (int s = 128; s > 0; s >>= 1) { if (t < s) sr[t] += sr[t + s]; __syncthreads(); }
    if (t == 0) scal[0] = sr[0];
    __syncthreads();

    float pv = 0.f;
    for (int i = t; i < 1024; i += 256) {
        float p = (float)counts[i] * (1.0f / 65536.0f);
        pv += p * logf(p + 1e-10f);
    }
    sr[t] = pv;
    __syncthreads();
    for (int s = 128; s > 0; s >>= 1) { if (t < s) sr[t] += sr[t + s]; __syncthreads(); }
    if (t == 0) out[OFF_PERP] = expf(-sr[0]);
}

// ---------------------------------------------------------------------------
// K4b: new_embedding_w = new_ema_w / cluster_size
__global__ void k_embnorm(const float* __restrict__ nema, const float* __restrict__ ncs,
                          const float* __restrict__ scal, float* __restrict__ embw) {
    int i = blockIdx.x * 256 + threadIdx.x;   // 65536
    float n = scal[0];
    int k = i >> 6;
    float cs = (ncs[k] + 1e-10f) / (n + 1.024e-7f) * n;   // (ncs+EPS)/(n+K*EPS)*n
    embw[i] = nema[i] / cs;
}

// ---------------------------------------------------------------------------
extern "C" void kernel_launch(void* const* d_in, const int* in_sizes, int n_in,
                              void* d_out, int out_size, void* d_ws, size_t ws_size,
                              hipStream_t stream) {
    const float* ze   = (const float*)d_in[0];
    const float* emb  = (const float*)d_in[1];
    const float* ecs  = (const float*)d_in[2];
    const float* emaw = (const float*)d_in[3];
    float* out = (float*)d_out;
    char*  ws  = (char*)d_ws;

    int*            idx    = (int*)(ws + WSO_IDX);
    float*          esq    = (float*)(ws + WSO_ESQ);
    float*          lossp  = (float*)(ws + WSO_LOSSP);
    int*            counts = (int*)(ws + WSO_CNT);
    float*          scal   = (float*)(ws + WSO_SCAL);
    unsigned short* ebh    = (unsigned short*)(ws + WSO_EBH);
    unsigned short* ebl    = (unsigned short*)(ws + WSO_EBL);
    float*          zc     = (float*)(ws + WSO_ZC);
    const int use_zc = (ws_size >= WS_NEED_ZC) ? 1 : 0;

    k_eprep  <<<32,   256, 0, stream>>>(emb, ebh, ebl, esq);
    k_assign <<<1024, 256, 0, stream>>>(ze, emb, esq, ebh, ebl, idx, lossp, zc, use_zc);
    k_stats  <<<1024, 256, 0, stream>>>(idx, zc, ze, emaw, ecs, out, counts, use_zc);
    k_out    <<<1024, 256, 0, stream>>>(idx, emb, out);
    k_scalars<<<1,    256, 0, stream>>>(lossp, counts, out + OFF_NCS, out, scal);
    k_embnorm<<<256,  256, 0, stream>>>(out + OFF_NEMA, out + OFF_NCS, scal, out + OFF_EMB);
}

// Round 8
// 187.481 us; speedup vs baseline: 4.2893x; 1.1406x over previous
//
#include <hip/hip_runtime.h>
#include <math.h>

// Problem constants
#define NTOT 65536   // B*H*W = 64*32*32
#define KCB  1024
#define DIM  64

typedef float fvec2 __attribute__((ext_vector_type(2)));
typedef float fvec4 __attribute__((ext_vector_type(4)));
typedef short sh8  __attribute__((ext_vector_type(8)));   // 8 bf16 = 4 VGPRs

// d_out layout (floats), concatenated return order
static const size_t OFF_Q    = 0;          // [64,64,32,32] = 4194304
static const size_t OFF_LOSS = 4194304;    // scalar
static const size_t OFF_PERP = 4194305;    // scalar
static const size_t OFF_ENC  = 4194306;    // [65536,1024] = 67108864
static const size_t OFF_EMB  = 71303170;   // [1024,64]
static const size_t OFF_NCS  = 71368706;   // [1024]
static const size_t OFF_NEMA = 71369730;   // [1024,64]

// ws layout (bytes)
static const size_t WSO_IDX   = 0;         // int[65536]
static const size_t WSO_ESQ   = 262144;    // float[1024]
static const size_t WSO_LOSSP = 266240;    // float[1024]
static const size_t WSO_CNT   = 270336;    // int[1024]
static const size_t WSO_SCAL  = 274432;    // float[8]
static const size_t WSO_EBH   = 278528;    // ushort[65536] e_hi, B-frag-major
static const size_t WSO_EBL   = 409600;    // ushort[65536] e_lo
static const size_t WSO_ZC    = 540672;    // float[65536*64] (optional compact z)
static const size_t WS_NEED_ZC = 540672 + (size_t)NTOT * DIM * 4;

// bf16 round-to-nearest-even split helpers
__device__ __forceinline__ unsigned short f2bf(float f) {
    unsigned u = __builtin_bit_cast(unsigned, f);
    return (unsigned short)((u + 0x7FFFu + ((u >> 16) & 1u)) >> 16);
}
__device__ __forceinline__ float bf2f(unsigned short h) {
    unsigned u = ((unsigned)h) << 16;
    return __builtin_bit_cast(float, u);
}

// ---------------------------------------------------------------------------
// K0: split e into bf16 hi/lo (B-frag-major) + fused e_sq via 8-lane reduce.
__global__ void k_eprep(const float* __restrict__ emb,
                        unsigned short* __restrict__ ebh,
                        unsigned short* __restrict__ ebl,
                        float* __restrict__ esq) {
    int gid = blockIdx.x * 256 + threadIdx.x;   // 32x256 = 8192
    int c = gid >> 3, ko8 = gid & 7;
    const fvec4* p = (const fvec4*)(emb + ((size_t)c << 6) + (ko8 << 3));
    fvec4 v0 = p[0], v1 = p[1];
    float f[8] = {v0.x, v0.y, v0.z, v0.w, v1.x, v1.y, v1.z, v1.w};
    sh8 h, l;
    float sq0 = 0.f, sq1 = 0.f;
#pragma unroll
    for (int j = 0; j < 8; ++j) {
        unsigned short hb = f2bf(f[j]);
        h[j] = (short)hb;
        l[j] = (short)f2bf(f[j] - bf2f(hb));
        if (j < 4) sq0 = fmaf(f[j], f[j], sq0); else sq1 = fmaf(f[j], f[j], sq1);
    }
    float sq = sq0 + sq1;
    sq += __shfl_xor(sq, 1, 64);
    sq += __shfl_xor(sq, 2, 64);
    sq += __shfl_xor(sq, 4, 64);
    if (ko8 == 0) esq[c] = sq;

    int ct = c >> 4, cl = c & 15, kc = ko8 >> 2, ko = ko8 & 3;
    size_t base = ((((size_t)ct << 1) + kc) << 9) + (((size_t)(ko << 4) + cl) << 3);
    *(sh8*)(ebh + base) = h;
    *(sh8*)(ebl + base) = l;
}

// ---------------------------------------------------------------------------
// K1: assignment via MFMA (bf16x3 split) -> idx, loss partial, compact z.
// Round-7 changes: depth-2 B prefetch (named reg sets, rule #20) and the
// 6-MFMA accumulation split into two independent 3-chains.
__global__ __launch_bounds__(256, 4)
void k_assign(const float* __restrict__ ze, const float* __restrict__ emb,
              const float* __restrict__ esq,
              const unsigned short* __restrict__ ebh,
              const unsigned short* __restrict__ ebl,
              int* __restrict__ idx_out, float* __restrict__ lossp,
              float* __restrict__ zc, int use_zc) {
    __shared__ float zt[4096];    // z tile [row][d] fp32
    __shared__ float etq[4096];   // merge arrays -> loss red
    __shared__ int   sfidx[64];

    const int tid  = threadIdx.x;
    const int blk  = blockIdx.x;
    const int b    = blk >> 4;
    const int hw0  = (blk & 15) << 6;
    const int n0   = blk << 6;
    const int lane = tid & 63;
    const int wave = tid >> 6;
    const int cg   = lane & 15;
    const int ko   = lane >> 4;

    // ---- stage z tile: global (coalesced float4 over hw) -> LDS [row][d] ----
#pragma unroll
    for (int j = 0; j < 4; ++j) {
        int idx = tid + (j << 8);
        int d = idx >> 4, r0 = (idx & 15) << 2;
        const fvec4 v = *(const fvec4*)(ze + (((size_t)(b << 6) + d) << 10) + hw0 + r0);
        zt[(r0 + 0) * 64 + d] = v.x;
        zt[(r0 + 1) * 64 + d] = v.y;
        zt[(r0 + 2) * 64 + d] = v.z;
        zt[(r0 + 3) * 64 + d] = v.w;
    }
    __syncthreads();

    // ---- A-fragments: z rows -> bf16 hi/lo in registers ----
    const int arow = (wave << 4) + cg;
    sh8 Ah0, Ah1, Al0, Al1;
#pragma unroll
    for (int j = 0; j < 8; ++j) {
        float f0 = zt[arow * 64 + (ko << 3) + j];
        float f1 = zt[arow * 64 + 32 + (ko << 3) + j];
        unsigned short h0 = f2bf(f0), h1 = f2bf(f1);
        Ah0[j] = (short)h0;  Al0[j] = (short)f2bf(f0 - bf2f(h0));
        Ah1[j] = (short)h1;  Al1[j] = (short)f2bf(f1 - bf2f(h1));
    }

    // ---- per-row-slot top-2 tracking (4 C rows per lane) ----
    float tb[4]  = {3.4e38f, 3.4e38f, 3.4e38f, 3.4e38f};
    float ts2[4] = {3.4e38f, 3.4e38f, 3.4e38f, 3.4e38f};
    int ti1[4] = {0, 0, 0, 0};
    int ti2[4] = {0, 0, 0, 0};

    const size_t lb = (size_t)lane << 3;
#define LOADB(d0, d1, d2, d3, ctv)                                  \
    { size_t o_ = ((size_t)(ctv) << 10) + lb;                       \
      d0 = *(const sh8*)(ebh + o_);                                 \
      d1 = *(const sh8*)(ebh + o_ + 512);                           \
      d2 = *(const sh8*)(ebl + o_);                                 \
      d3 = *(const sh8*)(ebl + o_ + 512); }

#define FOLD(ctv, acc)                                              \
    { const int code_ = ((ctv) << 4) + cg;                          \
      const float es_ = esq[code_];                                 \
      _Pragma("unroll")                                             \
      for (int rg = 0; rg < 4; ++rg) {                              \
          float s_ = fmaf((acc)[rg], -2.0f, es_);                   \
          bool c1 = s_ < tb[rg];                                    \
          bool c2 = s_ < ts2[rg];                                   \
          ti2[rg] = c1 ? ti1[rg] : (c2 ? code_ : ti2[rg]);          \
          ts2[rg] = c1 ? tb[rg] : (c2 ? s_ : ts2[rg]);              \
          ti1[rg] = c1 ? code_ : ti1[rg];                           \
          tb[rg]  = c1 ? s_ : tb[rg];                               \
      } }

    sh8 b0h0, b0h1, b0l0, b0l1, b1h0, b1h1, b1l0, b1l1;
    LOADB(b0h0, b0h1, b0l0, b0l1, 0);
    LOADB(b1h0, b1h1, b1l0, b1l1, 1);

    for (int ct = 0; ct < 64; ct += 2) {
        // even tile (b0): two independent 3-chains
        fvec4 aa = {0.f, 0.f, 0.f, 0.f}, ab = {0.f, 0.f, 0.f, 0.f};
        aa = __builtin_amdgcn_mfma_f32_16x16x32_bf16(Ah0, b0h0, aa, 0, 0, 0);
        ab = __builtin_amdgcn_mfma_f32_16x16x32_bf16(Ah1, b0h1, ab, 0, 0, 0);
        aa = __builtin_amdgcn_mfma_f32_16x16x32_bf16(Ah0, b0l0, aa, 0, 0, 0);
        ab = __builtin_amdgcn_mfma_f32_16x16x32_bf16(Ah1, b0l1, ab, 0, 0, 0);
        aa = __builtin_amdgcn_mfma_f32_16x16x32_bf16(Al0, b0h0, aa, 0, 0, 0);
        ab = __builtin_amdgcn_mfma_f32_16x16x32_bf16(Al1, b0h1, ab, 0, 0, 0);
        if (ct + 2 < 64) LOADB(b0h0, b0h1, b0l0, b0l1, ct + 2);
        fvec4 acc0 = aa + ab;
        FOLD(ct, acc0);

        // odd tile (b1)
        fvec4 ba = {0.f, 0.f, 0.f, 0.f}, bb = {0.f, 0.f, 0.f, 0.f};
        ba = __builtin_amdgcn_mfma_f32_16x16x32_bf16(Ah0, b1h0, ba, 0, 0, 0);
        bb = __builtin_amdgcn_mfma_f32_16x16x32_bf16(Ah1, b1h1, bb, 0, 0, 0);
        ba = __builtin_amdgcn_mfma_f32_16x16x32_bf16(Ah0, b1l0, ba, 0, 0, 0);
        bb = __builtin_amdgcn_mfma_f32_16x16x32_bf16(Ah1, b1l1, bb, 0, 0, 0);
        ba = __builtin_amdgcn_mfma_f32_16x16x32_bf16(Al0, b1h0, ba, 0, 0, 0);
        bb = __builtin_amdgcn_mfma_f32_16x16x32_bf16(Al1, b1h1, bb, 0, 0, 0);
        if (ct + 3 < 64) LOADB(b1h0, b1h1, b1l0, b1l1, ct + 3);
        fvec4 acc1 = ba + bb;
        FOLD(ct + 1, acc1);
    }
#undef LOADB
#undef FOLD

    // ---- merge 16 col-lane partials per row (etq: [16][64] x4 arrays) ----
    float* mb  = etq;
    float* ms2 = etq + 1024;
    int*   mi1 = (int*)(etq + 2048);
    int*   mi2 = (int*)(etq + 3072);
#pragma unroll
    for (int rg = 0; rg < 4; ++rg) {
        int row = (wave << 4) + (ko << 2) + rg;
        mb [(cg << 6) + row] = tb[rg];
        ms2[(cg << 6) + row] = ts2[rg];
        mi1[(cg << 6) + row] = ti1[rg];
        mi2[(cg << 6) + row] = ti2[rg];
    }
    __syncthreads();

    if (tid < 64) {
        const int r = tid;
        float fb = mb[r], fs2 = ms2[r];
        int fi1 = mi1[r], fi2 = mi2[r];
#pragma unroll
        for (int p = 1; p < 16; ++p) {
            float ob = mb[(p << 6) + r], os2 = ms2[(p << 6) + r];
            int oi1 = mi1[(p << 6) + r], oi2 = mi2[(p << 6) + r];
            if (ob < fb)       { fs2 = fb; fi2 = fi1; fb = ob; fi1 = oi1; }
            else if (ob < fs2) { fs2 = ob; fi2 = oi1; }
            if (os2 < fs2)     { fs2 = os2; fi2 = oi2; }
        }
        if (fs2 - fb < 2e-2f) {
            double d1 = 0.0, d2 = 0.0;
            const float* e1 = emb + (size_t)fi1 * 64;
            const float* e2 = emb + (size_t)fi2 * 64;
            for (int d = 0; d < 64; ++d) {
                double zd = (double)zt[r * 64 + d];
                double q1 = zd - (double)e1[d];
                double q2 = zd - (double)e2[d];
                d1 += q1 * q1;
                d2 += q2 * q2;
            }
            if ((d2 < d1) || (d2 == d1 && fi2 < fi1)) fi1 = fi2;
        }
        sfidx[r] = fi1;
        idx_out[n0 + r] = fi1;
    }
    __syncthreads();

    // ---- loss partial + compact z (cached: k_tail stats re-reads zc) ----
    float lacc = 0.f;
    for (int i = tid; i < 4096; i += 256) {
        int r = i >> 6, d = i & 63;
        float e  = emb[(size_t)sfidx[r] * 64 + d];
        float zv = zt[r * 64 + d];
        float df = e - zv;
        lacc = fmaf(df, df, lacc);
        if (use_zc) zc[(((size_t)(n0 + r)) << 6) + d] = zv;
    }
    __syncthreads();

    float* lred = etq;
    lred[tid] = lacc;
    __syncthreads();
    for (int s = 128; s > 0; s >>= 1) {
        if (tid < s) lred[tid] += lred[tid + s];
        __syncthreads();
    }
    if (tid == 0) lossp[blk] = lred[0];
}

// ---------------------------------------------------------------------------
// K2: merged tail — blocks [0,1024): per-code stats (latency-bound);
// blocks [1024,2048): output streaming (write-bound). One dispatch so the
// two phases overlap on-chip (they stress different pipes; both only read
// idx). LDS union 17.4 KB -> 8 blocks/CU, whole grid co-resident.
__global__ __launch_bounds__(256)
void k_tail(const int* __restrict__ idx, const float* __restrict__ zcmp,
            const float* __restrict__ ze, const float* __restrict__ emaw,
            const float* __restrict__ ecs, const float* __restrict__ emb,
            float* __restrict__ out, int* __restrict__ counts, int use_zc) {
    __shared__ __align__(16) char smem[17424];
    const int t = threadIdx.x;

    if (blockIdx.x >= 1024) {
        // ---------------- out role ----------------
        const int blk = blockIdx.x - 1024;
        const int b   = blk >> 4;
        const int hw0 = (blk & 15) << 6;
        const int n0  = blk << 6;
        int*   sfidx = (int*)smem;            // 64
        float* qt    = (float*)(smem + 256);  // 64*65

        if (t < 64) sfidx[t] = idx[n0 + t];
        __syncthreads();

        for (int i = t; i < 4096; i += 256) {
            int r = i >> 6, d = i & 63;
            qt[d * 65 + r] = emb[(size_t)sfidx[r] * 64 + d];
        }

        fvec2* enc2 = (fvec2*)(out + OFF_ENC);
        for (int i = t; i < 32768; i += 256) {   // 64 rows x 512 fvec2
            int r = i >> 9, c2 = i & 511;
            int fi = sfidx[r];
            int cb = c2 << 1;
            fvec2 v;
            v.x = (fi == cb)     ? 1.0f : 0.0f;
            v.y = (fi == cb + 1) ? 1.0f : 0.0f;
            __builtin_nontemporal_store(v, &enc2[(size_t)(n0 + r) * 512 + c2]);
        }
        __syncthreads();

        for (int i = t; i < 4096; i += 256) {
            int d = i >> 6, r = i & 63;
            __builtin_nontemporal_store(
                qt[d * 65 + r],
                &out[OFF_Q + ((size_t)((b << 6) + d) << 10) + hw0 + r]);
        }
        return;
    }

    // ---------------- stats role ----------------
    const int k    = blockIdx.x;
    const int g    = t >> 6;
    const int d    = t & 63;
    const int lane = t & 63;
    int*   s_list = (int*)smem;                    // 4096
    int*   s_wsum = (int*)(smem + 16384);          // 4
    float* s_red  = (float*)(smem + 16400);        // [4][64]

#define ZLOAD(n) (use_zc ? zcmp[((size_t)(n) << 6) + d] \
                         : ze[((((size_t)((n) >> 10) << 6) + d) << 10) + ((n) & 1023)])

    float a0 = 0.f, a1 = 0.f, a2 = 0.f, a3 = 0.f;
    int totalM = 0;

    for (int chunk = 0; chunk < 16; ++chunk) {
        const int base = chunk << 12;
        const int nb   = base + (t << 4);
        const int4* ip = (const int4*)(idx + nb);
        const int4 v0 = ip[0], v1 = ip[1], v2 = ip[2], v3 = ip[3];

        int c = 0;
        c += (v0.x == k) + (v0.y == k) + (v0.z == k) + (v0.w == k);
        c += (v1.x == k) + (v1.y == k) + (v1.z == k) + (v1.w == k);
        c += (v2.x == k) + (v2.y == k) + (v2.z == k) + (v2.w == k);
        c += (v3.x == k) + (v3.y == k) + (v3.z == k) + (v3.w == k);

        int inc = c;
#pragma unroll
        for (int off = 1; off < 64; off <<= 1) {
            int y = __shfl_up(inc, (unsigned)off, 64);
            if (lane >= off) inc += y;
        }
        if (lane == 63) s_wsum[g] = inc;
        __syncthreads();                            // (A)

        int wbase = 0;
#pragma unroll
        for (int w = 0; w < 4; ++w) wbase += (w < g) ? s_wsum[w] : 0;
        const int M = s_wsum[0] + s_wsum[1] + s_wsum[2] + s_wsum[3];
        int pos = wbase + inc - c;

        if (v0.x == k) s_list[pos++] = nb + 0;
        if (v0.y == k) s_list[pos++] = nb + 1;
        if (v0.z == k) s_list[pos++] = nb + 2;
        if (v0.w == k) s_list[pos++] = nb + 3;
        if (v1.x == k) s_list[pos++] = nb + 4;
        if (v1.y == k) s_list[pos++] = nb + 5;
        if (v1.z == k) s_list[pos++] = nb + 6;
        if (v1.w == k) s_list[pos++] = nb + 7;
        if (v2.x == k) s_list[pos++] = nb + 8;
        if (v2.y == k) s_list[pos++] = nb + 9;
        if (v2.z == k) s_list[pos++] = nb + 10;
        if (v2.w == k) s_list[pos++] = nb + 11;
        if (v3.x == k) s_list[pos++] = nb + 12;
        if (v3.y == k) s_list[pos++] = nb + 13;
        if (v3.z == k) s_list[pos++] = nb + 14;
        if (v3.w == k) s_list[pos++] = nb + 15;
        __syncthreads();                            // (B)

        int j = g;
        for (; j + 12 < M; j += 16) {
            int n0_ = s_list[j], n1_ = s_list[j + 4];
            int n2_ = s_list[j + 8], n3_ = s_list[j + 12];
            float z0 = ZLOAD(n0_), z1 = ZLOAD(n1_);
            float z2 = ZLOAD(n2_), z3 = ZLOAD(n3_);
            a0 += z0; a1 += z1; a2 += z2; a3 += z3;
        }
        for (; j < M; j += 4) a0 += ZLOAD(s_list[j]);
        totalM += M;
        __syncthreads();                            // (C)
    }
#undef ZLOAD

    s_red[(g << 6) + d] = (a0 + a1) + (a2 + a3);
    __syncthreads();
    if (g == 0) {
        float s = ((s_red[d] + s_red[64 + d]) + s_red[128 + d]) + s_red[192 + d];
        out[OFF_NEMA + ((size_t)k << 6) + d] =
            fmaf(0.01f, s, 0.99f * emaw[((size_t)k << 6) + d]);
    }
    if (t == 0) {
        counts[k] = totalM;
        out[OFF_NCS + k] = fmaf(0.01f, (float)totalM, 0.99f * ecs[k]);
    }
}

// ---------------------------------------------------------------------------
// K4a: scalars — loss, n = sum(new_cluster_size), perplexity
__global__ void k_scalars(const float* __restrict__ lossp, const int* __restrict__ counts,
                          const float* __restrict__ ncs, float* __restrict__ out,
                          float* __restrict__ scal) {
    __shared__ float sr[256];
    const int t = threadIdx.x;

    float v = lossp[t] + lossp[t + 256] + lossp[t + 512] + lossp[t + 768];
    sr[t] = v;
    __syncthreads();
    for (int s = 128; s > 0; s >>= 1) { if (t < s) sr[t] += sr[t + s]; __syncthreads(); }
    if (t == 0) out[OFF_LOSS] = sr[0] * (0.25f / 4194304.0f);
    __syncthreads();

    v = ncs[t] + ncs[t + 256] + ncs[t + 512] + ncs[t + 768];
    sr[t] = v;
    __syncthreads();
    for (int s = 128; s > 0; s >>= 1) { if (t < s) sr[t] += sr[t + s]; __syncthreads(); }
    if (t == 0) scal[0] = sr[0];
    __syncthreads();

    float pv = 0.f;
    for (int i = t; i < 1024; i += 256) {
        float p = (float)counts[i] * (1.0f / 65536.0f);
        pv += p * logf(p + 1e-10f);
    }
    sr[t] = pv;
    __syncthreads();
    for (int s = 128; s > 0; s >>= 1) { if (t < s) sr[t] += sr[t + s]; __syncthreads(); }
    if (t == 0) out[OFF_PERP] = expf(-sr[0]);
}

// ---------------------------------------------------------------------------
// K4b: new_embedding_w = new_ema_w / cluster_size
__global__ void k_embnorm(const float* __restrict__ nema, const float* __restrict__ ncs,
                          const float* __restrict__ scal, float* __restrict__ embw) {
    int i = blockIdx.x * 256 + threadIdx.x;   // 65536
    float n = scal[0];
    int k = i >> 6;
    float cs = (ncs[k] + 1e-10f) / (n + 1.024e-7f) * n;   // (ncs+EPS)/(n+K*EPS)*n
    embw[i] = nema[i] / cs;
}

// ---------------------------------------------------------------------------
extern "C" void kernel_launch(void* const* d_in, const int* in_sizes, int n_in,
                              void* d_out, int out_size, void* d_ws, size_t ws_size,
                              hipStream_t stream) {
    const float* ze   = (const float*)d_in[0];
    const float* emb  = (const float*)d_in[1];
    const float* ecs  = (const float*)d_in[2];
    const float* emaw = (const float*)d_in[3];
    float* out = (float*)d_out;
    char*  ws  = (char*)d_ws;

    int*            idx    = (int*)(ws + WSO_IDX);
    float*          esq    = (float*)(ws + WSO_ESQ);
    float*          lossp  = (float*)(ws + WSO_LOSSP);
    int*            counts = (int*)(ws + WSO_CNT);
    float*          scal   = (float*)(ws + WSO_SCAL);
    unsigned short* ebh    = (unsigned short*)(ws + WSO_EBH);
    unsigned short* ebl    = (unsigned short*)(ws + WSO_EBL);
    float*          zc     = (float*)(ws + WSO_ZC);
    const int use_zc = (ws_size >= WS_NEED_ZC) ? 1 : 0;

    k_eprep  <<<32,   256, 0, stream>>>(emb, ebh, ebl, esq);
    k_assign <<<1024, 256, 0, stream>>>(ze, emb, esq, ebh, ebl, idx, lossp, zc, use_zc);
    k_tail   <<<2048, 256, 0, stream>>>(idx, zc, ze, emaw, ecs, emb, out, counts, use_zc);
    k_scalars<<<1,    256, 0, stream>>>(lossp, counts, out + OFF_NCS, out, scal);
    k_embnorm<<<256,  256, 0, stream>>>(out + OFF_NEMA, out + OFF_NCS, scal, out + OFF_EMB);
}